// Round 3
// baseline (14140.195 us; speedup 1.0000x reference)
//
#include <hip/hip_runtime.h>
#include <stdint.h>

typedef unsigned short u16;
typedef unsigned int u32;
typedef __attribute__((ext_vector_type(8))) short bf16x8;
typedef __attribute__((ext_vector_type(4))) float f32x4;

#define DEV __device__ __forceinline__

#define NB 512   // batch
#define NT 64    // time
#define NE 1536  // embed
#define NH 512   // hid == deter
#define NS 32    // stoch

// ---- workspace layout (bytes) ----
static constexpr size_t OFF_EOBS   = 0;                                  // [T][B][512] f32 = 64MB
static constexpr size_t OFF_XX     = OFF_EOBS + (size_t)NT*NB*512*4;     // [512][512] bf16 (x)
static constexpr size_t OFF_XD     = OFF_XX + (size_t)512*512*2;         // [2][512][512] bf16 (deter dbuf)
static constexpr size_t OFF_DF     = OFF_XD + (size_t)2*512*512*2;       // [512][512] f32 deter carry
static constexpr size_t OFF_ACC    = OFF_DF + (size_t)512*512*4;         // [512][512] f32 obs pre-LN
static constexpr size_t OFF_LNP    = OFF_ACC + (size_t)512*512*4;        // [32][16][8][2] f32
static constexpr size_t OFF_D0     = OFF_LNP + (size_t)32*16*8*2*4;      // [512] f32
static constexpr size_t OFF_S0     = OFF_D0 + 512*4;                     // [32] f32 (pad 256)
static constexpr size_t OFF_BAR    = OFF_S0 + 256;                       // u32 barrier (pad 256)
static constexpr size_t OFF_WINPT  = OFF_BAR + 256;                      // 32cg x 2kk swizzled
static constexpr size_t OFF_WGRUT  = OFF_WINPT + (size_t)512*64*2;       // 96cg x 32kk
static constexpr size_t OFF_WIMGT  = OFF_WGRUT + (size_t)1536*1024*2;    // 32cg x 16kk
static constexpr size_t OFF_WOBSDT = OFF_WIMGT + (size_t)512*512*2;      // 32cg x 16kk
static constexpr size_t OFF_WOBSET = OFF_WOBSDT + (size_t)512*512*2;     // 32cg x 48kk
static constexpr size_t OFF_WIMST  = OFF_WOBSET + (size_t)512*1536*2;    // 4cg x 16kk
static constexpr size_t OFF_WOSTT  = OFF_WIMST + (size_t)64*512*2;       // 4cg x 16kk
static constexpr size_t WS_NEED    = OFF_WOSTT + (size_t)64*512*2;       // ~76.8 MB

DEV u16 f2b(float f) {
  u32 u = __builtin_bit_cast(u32, f);
  u32 r = (u + 0x7FFFu + ((u >> 16) & 1u)) >> 16;
  return (u16)r;
}
DEV float b2f(u16 h) { u32 u = (u32)h << 16; return __builtin_bit_cast(float, u); }
DEV u32 pk2(float a, float b) { return (u32)f2b(a) | ((u32)f2b(b) << 16); }
DEV float sigf(float x) { return 1.f / (1.f + __expf(-x)); }
DEV float siluf(float x) { return x * sigf(x); }
DEV float softplusf(float x) { return (x > 20.f) ? x : log1pf(__expf(x)); }
DEV f32x4 mfma16(bf16x8 a, bf16x8 b, f32x4 c) {
  return __builtin_amdgcn_mfma_f32_16x16x32_bf16(a, b, c, 0, 0, 0);
}
// swizzled B-fragment layout: element i of (colgrp,kk,lane) group =
//   W[kk*32 + (lane>>4)*8 + i][colgrp*16 + (lane&15)]
DEV size_t bswz(int colgrp, int kkmax, int kk, int lane) {
  return (((size_t)colgrp * kkmax + kk) * 64 + lane) * 8;
}

// device-wide barrier: monotonic counter, 256 blocks
DEV void gbar(u32* bar, u32 target) {
  __syncthreads();
  __threadfence();
  if (threadIdx.x == 0) {
    __hip_atomic_fetch_add(bar, 1u, __ATOMIC_RELEASE, __HIP_MEMORY_SCOPE_AGENT);
    u32 v = __hip_atomic_load(bar, __ATOMIC_ACQUIRE, __HIP_MEMORY_SCOPE_AGENT);
    while (v < target) {
      __builtin_amdgcn_s_sleep(2);
      v = __hip_atomic_load(bar, __ATOMIC_ACQUIRE, __HIP_MEMORY_SCOPE_AGENT);
    }
  }
  __syncthreads();
  __threadfence();
}

// ---------------- weight conversion: f32 -> bf16, MFMA-fragment-swizzled ----------------
__global__ __launch_bounds__(256) void k_convert(
    const float* __restrict__ W_inp, const float* __restrict__ W_gru,
    const float* __restrict__ W_img, const float* __restrict__ W_obs,
    const float* __restrict__ W_ims, const float* __restrict__ W_ostat,
    char* __restrict__ ws) {
  if (blockIdx.x == 0 && threadIdx.x == 0) *(volatile u32*)(ws + OFF_BAR) = 0u;
  u16* winpT  = (u16*)(ws + OFF_WINPT);
  u16* wgruT  = (u16*)(ws + OFF_WGRUT);
  u16* wimgT  = (u16*)(ws + OFF_WIMGT);
  u16* wobsdT = (u16*)(ws + OFF_WOBSDT);
  u16* wobseT = (u16*)(ws + OFF_WOBSET);
  u16* wimsT  = (u16*)(ws + OFF_WIMST);
  u16* wostT  = (u16*)(ws + OFF_WOSTT);
  int o = blockIdx.x * 256 + threadIdx.x;
  if (o < 32768) {  // winp: K=64(pad from 38), N=512, KK=2
    int i = o & 7, lane = (o >> 3) & 63, rem = o >> 9;
    int kk = rem & 1, cg = rem >> 1;
    int col = cg*16 + (lane & 15), k = kk*32 + (lane >> 4)*8 + i;
    winpT[o] = (k < 38) ? f2b(W_inp[k*512 + col]) : (u16)0;
    return;
  }
  o -= 32768;
  if (o < 1572864) {  // wgru: K=1024, N=1536, KK=32
    int i = o & 7, lane = (o >> 3) & 63, rem = o >> 9;
    int kk = rem & 31, cg = rem >> 5;
    int col = cg*16 + (lane & 15), k = kk*32 + (lane >> 4)*8 + i;
    wgruT[o] = f2b(W_gru[(size_t)k*1536 + col]);
    return;
  }
  o -= 1572864;
  if (o < 262144) {  // wimg: K=512, N=512, KK=16
    int i = o & 7, lane = (o >> 3) & 63, rem = o >> 9;
    int kk = rem & 15, cg = rem >> 4;
    int col = cg*16 + (lane & 15), k = kk*32 + (lane >> 4)*8 + i;
    wimgT[o] = f2b(W_img[k*512 + col]);
    return;
  }
  o -= 262144;
  if (o < 262144) {  // wobsd: K=512, N=512, KK=16
    int i = o & 7, lane = (o >> 3) & 63, rem = o >> 9;
    int kk = rem & 15, cg = rem >> 4;
    int col = cg*16 + (lane & 15), k = kk*32 + (lane >> 4)*8 + i;
    wobsdT[o] = f2b(W_obs[k*512 + col]);
    return;
  }
  o -= 262144;
  if (o < 786432) {  // wobse: K=1536, N=512, KK=48
    int i = o & 7, lane = (o >> 3) & 63, rem = o >> 9;
    int kk = rem % 48, cg = rem / 48;
    int col = cg*16 + (lane & 15), k = kk*32 + (lane >> 4)*8 + i;
    wobseT[o] = f2b(W_obs[(size_t)(512 + k)*512 + col]);
    return;
  }
  o -= 786432;
  if (o < 32768) {  // wims: K=512, N=64, KK=16
    int i = o & 7, lane = (o >> 3) & 63, rem = o >> 9;
    int kk = rem & 15, cg = rem >> 4;
    int col = cg*16 + (lane & 15), k = kk*32 + (lane >> 4)*8 + i;
    wimsT[o] = f2b(W_ims[k*64 + col]);
    return;
  }
  o -= 32768;
  {  // wost: K=512, N=64, KK=16
    int i = o & 7, lane = (o >> 3) & 63, rem = o >> 9;
    int kk = rem & 15, cg = rem >> 4;
    int col = cg*16 + (lane & 15), k = kk*32 + (lane >> 4)*8 + i;
    wostT[o] = f2b(W_ostat[k*64 + col]);
  }
}

// ---------------- initial state ----------------
__global__ __launch_bounds__(256) void k_init_a(
    const float* __restrict__ W_init, const float* __restrict__ W_img,
    const float* __restrict__ g_img, const float* __restrict__ b_img,
    const float* __restrict__ W_ims, const float* __restrict__ b_ims,
    char* __restrict__ ws) {
  __shared__ float DL[512];
  __shared__ float HL[512];
  __shared__ float RED[256];
  float* d0 = (float*)(ws + OFF_D0);
  float* s0 = (float*)(ws + OFF_S0);
  const int t = threadIdx.x;
  for (int j = t; j < 512; j += 256) { float v = tanhf(W_init[j]); DL[j] = v; d0[j] = v; }
  __syncthreads();
  float pre0 = 0.f, pre1 = 0.f;
  for (int k = 0; k < 512; ++k) {
    float dv = DL[k];
    pre0 += dv * W_img[k*512 + t];
    pre1 += dv * W_img[k*512 + t + 256];
  }
  RED[t] = pre0 + pre1;
  __syncthreads();
  for (int s = 128; s > 0; s >>= 1) { if (t < s) RED[t] += RED[t + s]; __syncthreads(); }
  float m = RED[0] * (1.f/512.f);
  __syncthreads();
  RED[t] = pre0*pre0 + pre1*pre1;
  __syncthreads();
  for (int s = 128; s > 0; s >>= 1) { if (t < s) RED[t] += RED[t + s]; __syncthreads(); }
  float var = RED[0] * (1.f/512.f) - m*m;
  float inv = rsqrtf(var + 1e-3f);
  HL[t]       = siluf((pre0 - m)*inv*g_img[t] + b_img[t]);
  HL[t + 256] = siluf((pre1 - m)*inv*g_img[t+256] + b_img[t+256]);
  __syncthreads();
  if (t < 32) {
    float s = 0.f;
    for (int k = 0; k < 512; ++k) s += HL[k] * W_ims[k*64 + t];
    s0[t] = s + b_ims[t];
  }
}

// ---------------- phase 1: E_obs[t][b][:] = embed[b][t][:] @ W_obs[512:,:] ----------------
__global__ __launch_bounds__(256) void k_phase1(
    const float* __restrict__ embed, char* __restrict__ ws) {
  const u16* wobse = (const u16*)(ws + OFF_WOBSET);
  float* eobs = (float*)(ws + OFF_EOBS);
  __shared__ u16 AL[32 * 40];
  const int tid = threadIdx.x;
  const int mb = blockIdx.x;   // 0..1023
  const int w = tid >> 6, l = tid & 63, l15 = l & 15, lk = l >> 4;
  const f32x4 fz = {0.f, 0.f, 0.f, 0.f};
  f32x4 acc[2][8];
  for (int a = 0; a < 2; ++a) for (int f = 0; f < 8; ++f) acc[a][f] = fz;
  const int srow = tid >> 3, sk4 = (tid & 7) * 4;
  const float* abase = embed + (size_t)(mb*32 + srow)*1536 + sk4;
  u16* adst = AL + srow*40 + sk4;
  for (int kk = 0; kk < 48; ++kk) {
    __syncthreads();
    {
      float4 v = *(const float4*)(abase + kk*32);
      uint2 q; q.x = pk2(v.x, v.y); q.y = pk2(v.z, v.w);
      *(uint2*)adst = q;
    }
    __syncthreads();
    bf16x8 af0 = *(const bf16x8*)(AL + l15*40 + lk*8);
    bf16x8 af1 = *(const bf16x8*)(AL + (16 + l15)*40 + lk*8);
    for (int f = 0; f < 8; ++f) {
      bf16x8 bf = *(const bf16x8*)(wobse + bswz(w*8 + f, 48, kk, l));
      acc[0][f] = mfma16(af0, bf, acc[0][f]);
      acc[1][f] = mfma16(af1, bf, acc[1][f]);
    }
  }
  for (int ar = 0; ar < 2; ++ar)
    for (int f = 0; f < 8; ++f) {
      int col = w*128 + f*16 + l15;
      for (int r = 0; r < 4; ++r) {
        int row = mb*32 + ar*16 + lk*4 + r;  // row = b*64 + t
        int bb = row >> 6, tt = row & 63;
        __builtin_nontemporal_store(acc[ar][f][r],
            eobs + ((size_t)tt*512 + bb)*512 + col);
      }
    }
}

// ---------------- persistent scan: 256 blocks x 256 threads, 3 device barriers/step ----------------
__global__ __launch_bounds__(256, 1) void k_scan(
    const float* __restrict__ action, const float* __restrict__ reset,
    const float* __restrict__ g_inp, const float* __restrict__ b_inp,
    const float* __restrict__ g_obs, const float* __restrict__ b_obs,
    const float* __restrict__ b_ostat, const float* __restrict__ npost,
    float* __restrict__ out, char* __restrict__ ws) {
  const u16* WINP  = (const u16*)(ws + OFF_WINPT);
  const u16* WGRU  = (const u16*)(ws + OFF_WGRUT);
  const u16* WOBSD = (const u16*)(ws + OFF_WOBSDT);
  const u16* WOST  = (const u16*)(ws + OFF_WOSTT);
  const float* eobs = (const float*)(ws + OFF_EOBS);
  u16* XX = (u16*)(ws + OFF_XX);
  u16* XD = (u16*)(ws + OFF_XD);
  float* DF = (float*)(ws + OFF_DF);
  float* ACC = (float*)(ws + OFF_ACC);
  float* LNP = (float*)(ws + OFF_LNP);
  const float* d0 = (const float*)(ws + OFF_D0);
  const float* s0 = (const float*)(ws + OFF_S0);
  u32* bar = (u32*)(ws + OFF_BAR);

  __shared__ float STOL[16*32];     // stoch carry (block-private, b<32)
  __shared__ float RL[16];
  __shared__ u16 CIN[16*72];
  __shared__ float LNB[4][16][2];
  __shared__ u16 HLDS[16*520];
  __shared__ float STL[16*64];
  __shared__ float LNS[16][8][2];
  __shared__ float MIV[16][2];

  const int tid = threadIdx.x;
  const int b = blockIdx.x;
  const int w = tid >> 6, l = tid & 63, l15 = l & 15, lk = l >> 4;
  const f32x4 fz = {0.f,0.f,0.f,0.f};
  u32 tgt = 0;

  // PG roles: xcd-aware col mapping
  const int xcd = b & 7, bj = b >> 3;
  const int rg2 = bj & 15;              // 32-row group
  const int cc  = xcd*2 + (bj >> 4);    // 32-jcol chunk (0..15)
  const int pg_m = w & 1, pg_n = w >> 1;
  // PO roles
  const int oc = xcd, rg = bj;          // 64-col chunk, 16-row group

  // PX: input MLP for step t (blocks b<32 only)
  auto px = [&](int t) {
    const int r0 = b*16;
    u16* XDb = XD + (size_t)(t & 1)*512*512;
    if (tid < 16) RL[tid] = reset[(size_t)(r0 + tid)*NT + t];
    __syncthreads();
    // stoch blend
    for (int u = tid; u < 512; u += 256) {
      int rr = u >> 5, i2 = u & 31;
      float r = RL[rr];
      if (r != 0.f) STOL[rr*32+i2] = STOL[rr*32+i2]*(1.f-r) + s0[i2]*r;
    }
    // deter blend (skipped per-row when r==0)
    for (int u = tid; u < 8192; u += 256) {
      int rr = u >> 9, jj = u & 511;
      float r = RL[rr];
      if (r != 0.f) {
        size_t idx = (size_t)(r0+rr)*512 + jj;
        float v = DF[idx]*(1.f-r) + d0[jj]*r;
        DF[idx] = v;
        XDb[idx] = f2b(v);
      }
    }
    __syncthreads();
    // cin = [stoch | action*(1-r) | 0pad]  (K padded to 64)
    for (int u = tid; u < 512; u += 256) {
      int rr = u >> 5, kp = (u & 31)*2;
      float r = RL[rr], onem = 1.f - r;
      int k1 = kp + 1;
      float v0 = (kp < 32) ? STOL[rr*32+kp]
               : (kp < 38 ? action[((size_t)(r0+rr)*NT + t)*6 + kp-32]*onem : 0.f);
      float v1 = (k1 < 32) ? STOL[rr*32+k1]
               : (k1 < 38 ? action[((size_t)(r0+rr)*NT + t)*6 + k1-32]*onem : 0.f);
      *(u32*)(CIN + rr*72 + kp) = pk2(v0, v1);
    }
    __syncthreads();
    // x GEMM (K=64) + LN + silu -> XX
    f32x4 ai[8];
    for (int f = 0; f < 8; ++f) ai[f] = fz;
    for (int kk = 0; kk < 2; ++kk) {
      bf16x8 af = *(const bf16x8*)(CIN + l15*72 + kk*32 + lk*8);
      for (int f = 0; f < 8; ++f) {
        bf16x8 bf = *(const bf16x8*)(WINP + bswz(w*8 + f, 2, kk, l));
        ai[f] = mfma16(af, bf, ai[f]);
      }
    }
    for (int r = 0; r < 4; ++r) {
      float s1 = 0.f, s2 = 0.f;
      for (int f = 0; f < 8; ++f) { float v = ai[f][r]; s1 += v; s2 += v*v; }
      for (int d = 1; d < 16; d <<= 1) { s1 += __shfl_xor(s1, d); s2 += __shfl_xor(s2, d); }
      if (l15 == 0) { LNB[w][lk*4 + r][0] = s1; LNB[w][lk*4 + r][1] = s2; }
    }
    __syncthreads();
    float mr[4], ir[4];
    for (int r = 0; r < 4; ++r) {
      int row = lk*4 + r;
      float S1 = LNB[0][row][0]+LNB[1][row][0]+LNB[2][row][0]+LNB[3][row][0];
      float S2 = LNB[0][row][1]+LNB[1][row][1]+LNB[2][row][1]+LNB[3][row][1];
      float m = S1 * (1.f/512.f);
      float var = S2 * (1.f/512.f) - m*m;
      mr[r] = m; ir[r] = rsqrtf(var + 1e-3f);
    }
    for (int f = 0; f < 8; ++f) {
      int col = w*128 + f*16 + l15;
      float gg = g_inp[col], bb = b_inp[col];
      for (int r = 0; r < 4; ++r) {
        float v = siluf((ai[f][r] - mr[r]) * ir[r] * gg + bb);
        XX[(size_t)(r0 + lk*4 + r)*512 + col] = f2b(v);
      }
    }
  };

  // ---- init: deter0/stoch0 + px(0) ----
  if (b < 32) {
    const int r0 = b*16;
    for (int u = tid; u < 8192; u += 256) {
      int rr = u >> 9, jj = u & 511;
      float v = d0[jj];
      DF[(size_t)(r0+rr)*512 + jj] = v;
      XD[(size_t)(r0+rr)*512 + jj] = f2b(v);      // buffer 0
    }
    for (int u = tid; u < 512; u += 256) { int rr=u>>5, i2=u&31; STOL[rr*32+i2] = s0[i2]; }
    __syncthreads();
    px(0);
  }
  tgt += 256; gbar(bar, tgt);

  for (int t = 0; t < NT; ++t) {
    const u16* XDin = XD + (size_t)(t & 1)*512*512;
    u16* XDout = XD + (size_t)((t+1) & 1)*512*512;
    // ---- PG: GRU GEMM + gates ----
    {
      f32x4 ag0 = fz, ag1 = fz, ag2 = fz;
      const int arow0 = rg2*32 + pg_m*16;
      const u16* xrow = XX + (size_t)(arow0 + l15)*512 + lk*8;
      const u16* drow = XDin + (size_t)(arow0 + l15)*512 + lk*8;
      const int cg0 = cc*2 + pg_n;
      #pragma unroll 4
      for (int kk = 0; kk < 16; ++kk) {
        bf16x8 af = *(const bf16x8*)(xrow + kk*32);
        bf16x8 b0 = *(const bf16x8*)(WGRU + bswz(cg0, 32, kk, l));
        bf16x8 b1 = *(const bf16x8*)(WGRU + bswz(32 + cg0, 32, kk, l));
        bf16x8 b2 = *(const bf16x8*)(WGRU + bswz(64 + cg0, 32, kk, l));
        ag0 = mfma16(af, b0, ag0); ag1 = mfma16(af, b1, ag1); ag2 = mfma16(af, b2, ag2);
      }
      #pragma unroll 4
      for (int kk = 16; kk < 32; ++kk) {
        bf16x8 af = *(const bf16x8*)(drow + (kk-16)*32);
        bf16x8 b0 = *(const bf16x8*)(WGRU + bswz(cg0, 32, kk, l));
        bf16x8 b1 = *(const bf16x8*)(WGRU + bswz(32 + cg0, 32, kk, l));
        bf16x8 b2 = *(const bf16x8*)(WGRU + bswz(64 + cg0, 32, kk, l));
        ag0 = mfma16(af, b0, ag0); ag1 = mfma16(af, b1, ag1); ag2 = mfma16(af, b2, ag2);
      }
      const int jcol = cc*32 + pg_n*16 + l15;
      for (int r = 0; r < 4; ++r) {
        int row = arow0 + lk*4 + r;
        size_t idx = (size_t)row*512 + jcol;
        float dold = DF[idx];
        float rg_ = sigf(ag0[r]);
        float ca = tanhf(rg_ * ag1[r]);
        float up = sigf(ag2[r] - 1.f);
        float dn = up*ca + (1.f - up)*dold;
        DF[idx] = dn;
        XDout[idx] = f2b(dn);
        __builtin_nontemporal_store(dn, out + ((size_t)row*NT + t)*704 + 192 + jcol);
      }
    }
    tgt += 256; gbar(bar, tgt);

    // ---- PO: obs GEMM partial (16 rows x 64 cols) ----
    {
      const int col = oc*64 + w*16 + l15;
      float ev[4];
      for (int r = 0; r < 4; ++r)
        ev[r] = __builtin_nontemporal_load(
            eobs + ((size_t)t*512 + rg*16 + lk*4 + r)*512 + col);
      f32x4 ao = fz;
      const u16* abase = XDout + (size_t)(rg*16 + l15)*512 + lk*8;
      #pragma unroll 4
      for (int kk = 0; kk < 16; ++kk) {
        bf16x8 af = *(const bf16x8*)(abase + kk*32);
        bf16x8 bf = *(const bf16x8*)(WOBSD + bswz(oc*4 + w, 16, kk, l));
        ao = mfma16(af, bf, ao);
      }
      float s1p = 0.f, s2p = 0.f;
      for (int r = 0; r < 4; ++r) {
        float v = ao[r] + ev[r];
        ao[r] = v;
        ACC[(size_t)(rg*16 + lk*4 + r)*512 + col] = v;
      }
      for (int r = 0; r < 4; ++r) {
        float v = ao[r];
        float s1 = v, s2 = v*v;
        for (int d = 1; d < 16; d <<= 1) { s1 += __shfl_xor(s1, d); s2 += __shfl_xor(s2, d); }
        if (l15 == 0) { LNB[w][lk*4 + r][0] = s1; LNB[w][lk*4 + r][1] = s2; }
      }
      (void)s1p; (void)s2p;
      __syncthreads();
      if (tid < 16) {
        float S1 = LNB[0][tid][0]+LNB[1][tid][0]+LNB[2][tid][0]+LNB[3][tid][0];
        float S2 = LNB[0][tid][1]+LNB[1][tid][1]+LNB[2][tid][1]+LNB[3][tid][1];
        LNP[((size_t)rg*16 + tid)*16 + oc*2]     = S1;
        LNP[((size_t)rg*16 + tid)*16 + oc*2 + 1] = S2;
      }
    }
    tgt += 256; gbar(bar, tgt);

    // ---- PSX: LN finish + h + ostat + sample + next px ----
    if (b < 32) {
      const int r0 = b*16;
      if (tid < 128) {
        int row = tid >> 3, o = tid & 7;
        LNS[row][o][0] = LNP[((size_t)b*16 + row)*16 + o*2];
        LNS[row][o][1] = LNP[((size_t)b*16 + row)*16 + o*2 + 1];
      }
      __syncthreads();
      if (tid < 16) {
        float S1 = 0.f, S2 = 0.f;
        for (int o = 0; o < 8; ++o) { S1 += LNS[tid][o][0]; S2 += LNS[tid][o][1]; }
        float m = S1 * (1.f/512.f);
        float var = S2 * (1.f/512.f) - m*m;
        MIV[tid][0] = m; MIV[tid][1] = rsqrtf(var + 1e-3f);
      }
      __syncthreads();
      {
        int row = tid >> 4, c0 = (tid & 15)*32;
        float m = MIV[row][0], iv = MIV[row][1];
        const float4* arow4 = (const float4*)(ACC + (size_t)(r0+row)*512 + c0);
        const float4* g4 = (const float4*)(g_obs + c0);
        const float4* bb4 = (const float4*)(b_obs + c0);
        u16* hrow = HLDS + row*520 + c0;
        for (int q4 = 0; q4 < 8; ++q4) {
          float4 av = arow4[q4];
          float4 gv = g4[q4];
          float4 bv = bb4[q4];
          float v0 = siluf((av.x - m)*iv*gv.x + bv.x);
          float v1 = siluf((av.y - m)*iv*gv.y + bv.y);
          float v2 = siluf((av.z - m)*iv*gv.z + bv.z);
          float v3 = siluf((av.w - m)*iv*gv.w + bv.w);
          uint2 q; q.x = pk2(v0, v1); q.y = pk2(v2, v3);
          *(uint2*)(hrow + q4*4) = q;
        }
      }
      __syncthreads();
      {
        f32x4 q = fz;
        #pragma unroll 4
        for (int kk = 0; kk < 16; ++kk) {
          bf16x8 af = *(const bf16x8*)(HLDS + l15*520 + kk*32 + lk*8);
          bf16x8 bf = *(const bf16x8*)(WOST + bswz(w, 16, kk, l));
          q = mfma16(af, bf, q);
        }
        float bia = b_ostat[w*16 + l15];
        for (int r = 0; r < 4; ++r) STL[(lk*4 + r)*64 + w*16 + l15] = q[r] + bia;
      }
      __syncthreads();
      for (int u = tid; u < 512; u += 256) {
        int row = u >> 5, i = u & 31;
        float qm = STL[row*64 + i];
        float qs = softplusf(STL[row*64 + 32 + i]) + 0.1f;
        float ns = npost[((size_t)t*512 + r0 + row)*32 + i];
        float qst = qm + qs*ns;
        size_t ob = ((size_t)(r0 + row)*NT + t)*704;
        __builtin_nontemporal_store(qm, out + ob + i);
        __builtin_nontemporal_store(qs, out + ob + 32 + i);
        __builtin_nontemporal_store(qst, out + ob + 64 + i);
        STOL[row*32 + i] = qst;
      }
      __syncthreads();
      if (t < NT-1) px(t+1);
    }
    tgt += 256; gbar(bar, tgt);
  }
}

// ---------------- post: prior branch for all (b,t) ----------------
__global__ __launch_bounds__(256) void k_p3(
    const float* __restrict__ g_img, const float* __restrict__ b_img,
    const float* __restrict__ b_ims, const float* __restrict__ nprior,
    float* __restrict__ out, char* __restrict__ ws) {
  const u16* wimgT = (const u16*)(ws + OFF_WIMGT);
  const u16* wimsT = (const u16*)(ws + OFF_WIMST);
  __shared__ u16 AL[32 * 40];
  __shared__ u16 HL[32 * 520];
  __shared__ float LNB[4][32][2];
  __shared__ float STL[32 * 64];
  const int tid = threadIdx.x;
  const int mb = blockIdx.x;   // 0..1023
  const int w = tid >> 6, l = tid & 63, l15 = l & 15, lk = l >> 4;
  const f32x4 fz = {0.f,0.f,0.f,0.f};
  f32x4 acc[2][8];
  for (int rb = 0; rb < 2; ++rb) for (int f = 0; f < 8; ++f) acc[rb][f] = fz;
  const int srow = tid >> 3, sko = (tid & 7) * 4;
  const float* sbase = out + (size_t)(mb*32 + srow)*704 + 192 + sko;  // deter_n
  u16* sdst = AL + srow*40 + sko;
  for (int kk = 0; kk < 16; ++kk) {
    __syncthreads();
    {
      float4 v = *(const float4*)(sbase + kk*32);
      uint2 q; q.x = pk2(v.x, v.y); q.y = pk2(v.z, v.w);
      *(uint2*)sdst = q;
    }
    __syncthreads();
    bf16x8 af0 = *(const bf16x8*)(AL + l15*40 + lk*8);
    bf16x8 af1 = *(const bf16x8*)(AL + (16 + l15)*40 + lk*8);
    for (int f = 0; f < 8; ++f) {
      bf16x8 bf = *(const bf16x8*)(wimgT + bswz(w*8 + f, 16, kk, l));
      acc[0][f] = mfma16(af0, bf, acc[0][f]);
      acc[1][f] = mfma16(af1, bf, acc[1][f]);
    }
  }
  for (int rb = 0; rb < 2; ++rb) {
    for (int r = 0; r < 4; ++r) {
      float s1 = 0.f, s2 = 0.f;
      for (int f = 0; f < 8; ++f) { float v = acc[rb][f][r]; s1 += v; s2 += v*v; }
      for (int d = 1; d < 16; d <<= 1) { s1 += __shfl_xor(s1, d); s2 += __shfl_xor(s2, d); }
      if (l15 == 0) { LNB[w][rb*16 + lk*4 + r][0] = s1; LNB[w][rb*16 + lk*4 + r][1] = s2; }
    }
  }
  __syncthreads();
  for (int rb = 0; rb < 2; ++rb) {
    float mr[4], ir[4];
    for (int r = 0; r < 4; ++r) {
      int row = rb*16 + lk*4 + r;
      float S1 = LNB[0][row][0] + LNB[1][row][0] + LNB[2][row][0] + LNB[3][row][0];
      float S2 = LNB[0][row][1] + LNB[1][row][1] + LNB[2][row][1] + LNB[3][row][1];
      float m = S1 * (1.f/512.f);
      float var = S2 * (1.f/512.f) - m*m;
      mr[r] = m; ir[r] = rsqrtf(var + 1e-3f);
    }
    for (int f = 0; f < 8; ++f) {
      int col = w*128 + f*16 + l15;
      float gg = g_img[col], bb = b_img[col];
      for (int r = 0; r < 4; ++r) {
        float v = siluf((acc[rb][f][r] - mr[r]) * ir[r] * gg + bb);
        HL[(rb*16 + lk*4 + r)*520 + col] = f2b(v);
      }
    }
  }
  __syncthreads();
  f32x4 q0 = fz, q1 = fz;
  for (int kk = 0; kk < 16; ++kk) {
    bf16x8 bf = *(const bf16x8*)(wimsT + bswz(w, 16, kk, l));
    bf16x8 af0 = *(const bf16x8*)(HL + l15*520 + kk*32 + lk*8);
    bf16x8 af1 = *(const bf16x8*)(HL + (16 + l15)*520 + kk*32 + lk*8);
    q0 = mfma16(af0, bf, q0);
    q1 = mfma16(af1, bf, q1);
  }
  float bia = b_ims[w*16 + l15];
  for (int r = 0; r < 4; ++r) {
    STL[(lk*4 + r)*64 + w*16 + l15] = q0[r] + bia;
    STL[(16 + lk*4 + r)*64 + w*16 + l15] = q1[r] + bia;
  }
  __syncthreads();
  for (int it = tid; it < 1024; it += 256) {
    int row = it >> 5, i = it & 31;
    int grow = mb*32 + row;
    int bb = grow >> 6, tt = grow & 63;
    float pm = STL[row*64 + i];
    float ps = softplusf(STL[row*64 + 32 + i]) + 0.1f;
    float nr = nprior[((size_t)tt*512 + bb)*32 + i];
    float pst = pm + ps*nr;
    size_t ob = (size_t)grow*704;
    out[ob + 96 + i] = pm;
    out[ob + 128 + i] = ps;
    out[ob + 160 + i] = pst;
  }
}

extern "C" void kernel_launch(void* const* d_in, const int* in_sizes, int n_in,
                              void* d_out, int out_size, void* d_ws, size_t ws_size,
                              hipStream_t stream) {
  const float* embed   = (const float*)d_in[0];
  const float* action  = (const float*)d_in[1];
  const float* reset   = (const float*)d_in[2];
  const float* npost   = (const float*)d_in[3];
  const float* nprior  = (const float*)d_in[4];
  const float* W_inp   = (const float*)d_in[5];
  const float* g_inp   = (const float*)d_in[6];
  const float* b_inp   = (const float*)d_in[7];
  const float* W_gru   = (const float*)d_in[8];
  const float* W_img   = (const float*)d_in[9];
  const float* g_img   = (const float*)d_in[10];
  const float* b_img   = (const float*)d_in[11];
  const float* W_obs   = (const float*)d_in[12];
  const float* g_obs   = (const float*)d_in[13];
  const float* b_obs   = (const float*)d_in[14];
  const float* W_ims   = (const float*)d_in[15];
  const float* b_ims   = (const float*)d_in[16];
  const float* W_ostat = (const float*)d_in[17];
  const float* b_ostat = (const float*)d_in[18];
  const float* W_init  = (const float*)d_in[19];
  float* out = (float*)d_out;
  char* ws = (char*)d_ws;
  if (ws_size < WS_NEED) return;

  k_convert<<<11648, 256, 0, stream>>>(W_inp, W_gru, W_img, W_obs, W_ims, W_ostat, ws);
  k_init_a<<<1, 256, 0, stream>>>(W_init, W_img, g_img, b_img, W_ims, b_ims, ws);
  k_phase1<<<1024, 256, 0, stream>>>(embed, ws);
  k_scan<<<256, 256, 0, stream>>>(action, reset, g_inp, b_inp, g_obs, b_obs,
                                  b_ostat, npost, out, ws);
  k_p3<<<1024, 256, 0, stream>>>(g_img, b_img, b_ims, nprior, out, ws);
}

// Round 6
// 2546.480 us; speedup vs baseline: 5.5528x; 5.5528x over previous
//
#include <hip/hip_runtime.h>
#include <stdint.h>

typedef unsigned short u16;
typedef unsigned int u32;
typedef __attribute__((ext_vector_type(8))) short bf16x8;
typedef __attribute__((ext_vector_type(4))) float f32x4;

#define DEV __device__ __forceinline__

#define NB 512   // batch
#define NT 64    // time
#define NE 1536  // embed
#define NH 512   // hid == deter
#define NS 32    // stoch

// ---- workspace layout (bytes) ----
static constexpr size_t OFF_EOBS   = 0;                                  // [T][B][512] f32 = 64MB
static constexpr size_t OFF_XX     = OFF_EOBS + (size_t)NT*NB*512*4;     // [512][512] bf16 (x)
static constexpr size_t OFF_XD     = OFF_XX + (size_t)512*512*2;         // [2][512][512] bf16 deter dbuf
static constexpr size_t OFF_DF     = OFF_XD + (size_t)2*512*512*2;       // [512][512] f32 deter carry
static constexpr size_t OFF_D0     = OFF_DF + (size_t)512*512*4;         // [512] f32
static constexpr size_t OFF_S0     = OFF_D0 + 512*4;                     // [32] f32 (pad 256)
static constexpr size_t OFF_WINPT  = OFF_S0 + 256;                       // 32cg x 2kk swizzled
static constexpr size_t OFF_WGRUT  = OFF_WINPT + (size_t)512*64*2;       // 96cg x 32kk
static constexpr size_t OFF_WIMGT  = OFF_WGRUT + (size_t)1536*1024*2;    // 32cg x 16kk
static constexpr size_t OFF_WOBSDT = OFF_WIMGT + (size_t)512*512*2;      // 32cg x 16kk
static constexpr size_t OFF_WOBSET = OFF_WOBSDT + (size_t)512*512*2;     // 32cg x 48kk
static constexpr size_t OFF_WIMST  = OFF_WOBSET + (size_t)512*1536*2;    // 4cg x 16kk
static constexpr size_t OFF_WOSTT  = OFF_WIMST + (size_t)64*512*2;       // 4cg x 16kk
static constexpr size_t WS_NEED    = OFF_WOSTT + (size_t)64*512*2;       // ~74.5 MB

DEV u16 f2b(float f) {
  u32 u = __builtin_bit_cast(u32, f);
  u32 r = (u + 0x7FFFu + ((u >> 16) & 1u)) >> 16;
  return (u16)r;
}
DEV float b2f(u16 h) { u32 u = (u32)h << 16; return __builtin_bit_cast(float, u); }
DEV u32 pk2(float a, float b) { return (u32)f2b(a) | ((u32)f2b(b) << 16); }
DEV float sigf(float x) { return 1.f / (1.f + __expf(-x)); }
DEV float siluf(float x) { return x * sigf(x); }
DEV float softplusf(float x) { return (x > 20.f) ? x : log1pf(__expf(x)); }
DEV f32x4 mfma16(bf16x8 a, bf16x8 b, f32x4 c) {
  return __builtin_amdgcn_mfma_f32_16x16x32_bf16(a, b, c, 0, 0, 0);
}
// swizzled B-fragment layout: element i of (colgrp,kk,lane) group =
//   W[kk*32 + (lane>>4)*8 + i][colgrp*16 + (lane&15)]
DEV size_t bswz(int colgrp, int kkmax, int kk, int lane) {
  return (((size_t)colgrp * kkmax + kk) * 64 + lane) * 8;
}

// ---------------- weight conversion: f32 -> bf16, MFMA-fragment-swizzled ----------------
__global__ __launch_bounds__(256) void k_convert(
    const float* __restrict__ W_inp, const float* __restrict__ W_gru,
    const float* __restrict__ W_img, const float* __restrict__ W_obs,
    const float* __restrict__ W_ims, const float* __restrict__ W_ostat,
    char* __restrict__ ws) {
  u16* winpT  = (u16*)(ws + OFF_WINPT);
  u16* wgruT  = (u16*)(ws + OFF_WGRUT);
  u16* wimgT  = (u16*)(ws + OFF_WIMGT);
  u16* wobsdT = (u16*)(ws + OFF_WOBSDT);
  u16* wobseT = (u16*)(ws + OFF_WOBSET);
  u16* wimsT  = (u16*)(ws + OFF_WIMST);
  u16* wostT  = (u16*)(ws + OFF_WOSTT);
  int o = blockIdx.x * 256 + threadIdx.x;
  if (o < 32768) {  // winp: K=64(pad from 38), N=512, KK=2
    int i = o & 7, lane = (o >> 3) & 63, rem = o >> 9;
    int kk = rem & 1, cg = rem >> 1;
    int col = cg*16 + (lane & 15), k = kk*32 + (lane >> 4)*8 + i;
    winpT[o] = (k < 38) ? f2b(W_inp[k*512 + col]) : (u16)0;
    return;
  }
  o -= 32768;
  if (o < 1572864) {  // wgru: K=1024, N=1536, KK=32
    int i = o & 7, lane = (o >> 3) & 63, rem = o >> 9;
    int kk = rem & 31, cg = rem >> 5;
    int col = cg*16 + (lane & 15), k = kk*32 + (lane >> 4)*8 + i;
    wgruT[o] = f2b(W_gru[(size_t)k*1536 + col]);
    return;
  }
  o -= 1572864;
  if (o < 262144) {  // wimg
    int i = o & 7, lane = (o >> 3) & 63, rem = o >> 9;
    int kk = rem & 15, cg = rem >> 4;
    int col = cg*16 + (lane & 15), k = kk*32 + (lane >> 4)*8 + i;
    wimgT[o] = f2b(W_img[k*512 + col]);
    return;
  }
  o -= 262144;
  if (o < 262144) {  // wobsd
    int i = o & 7, lane = (o >> 3) & 63, rem = o >> 9;
    int kk = rem & 15, cg = rem >> 4;
    int col = cg*16 + (lane & 15), k = kk*32 + (lane >> 4)*8 + i;
    wobsdT[o] = f2b(W_obs[k*512 + col]);
    return;
  }
  o -= 262144;
  if (o < 786432) {  // wobse
    int i = o & 7, lane = (o >> 3) & 63, rem = o >> 9;
    int kk = rem % 48, cg = rem / 48;
    int col = cg*16 + (lane & 15), k = kk*32 + (lane >> 4)*8 + i;
    wobseT[o] = f2b(W_obs[(size_t)(512 + k)*512 + col]);
    return;
  }
  o -= 786432;
  if (o < 32768) {  // wims
    int i = o & 7, lane = (o >> 3) & 63, rem = o >> 9;
    int kk = rem & 15, cg = rem >> 4;
    int col = cg*16 + (lane & 15), k = kk*32 + (lane >> 4)*8 + i;
    wimsT[o] = f2b(W_ims[k*64 + col]);
    return;
  }
  o -= 32768;
  {  // wost
    int i = o & 7, lane = (o >> 3) & 63, rem = o >> 9;
    int kk = rem & 15, cg = rem >> 4;
    int col = cg*16 + (lane & 15), k = kk*32 + (lane >> 4)*8 + i;
    wostT[o] = f2b(W_ostat[k*64 + col]);
  }
}

// ---------------- initial state ----------------
__global__ __launch_bounds__(256) void k_init_a(
    const float* __restrict__ W_init, const float* __restrict__ W_img,
    const float* __restrict__ g_img, const float* __restrict__ b_img,
    const float* __restrict__ W_ims, const float* __restrict__ b_ims,
    char* __restrict__ ws) {
  __shared__ float DL[512];
  __shared__ float HL[512];
  __shared__ float RED[256];
  float* d0 = (float*)(ws + OFF_D0);
  float* s0 = (float*)(ws + OFF_S0);
  const int t = threadIdx.x;
  for (int j = t; j < 512; j += 256) { float v = tanhf(W_init[j]); DL[j] = v; d0[j] = v; }
  __syncthreads();
  float pre0 = 0.f, pre1 = 0.f;
  for (int k = 0; k < 512; ++k) {
    float dv = DL[k];
    pre0 += dv * W_img[k*512 + t];
    pre1 += dv * W_img[k*512 + t + 256];
  }
  RED[t] = pre0 + pre1;
  __syncthreads();
  for (int s = 128; s > 0; s >>= 1) { if (t < s) RED[t] += RED[t + s]; __syncthreads(); }
  float m = RED[0] * (1.f/512.f);
  __syncthreads();
  RED[t] = pre0*pre0 + pre1*pre1;
  __syncthreads();
  for (int s = 128; s > 0; s >>= 1) { if (t < s) RED[t] += RED[t + s]; __syncthreads(); }
  float var = RED[0] * (1.f/512.f) - m*m;
  float inv = rsqrtf(var + 1e-3f);
  HL[t]       = siluf((pre0 - m)*inv*g_img[t] + b_img[t]);
  HL[t + 256] = siluf((pre1 - m)*inv*g_img[t+256] + b_img[t+256]);
  __syncthreads();
  if (t < 32) {
    float s = 0.f;
    for (int k = 0; k < 512; ++k) s += HL[k] * W_ims[k*64 + t];
    s0[t] = s + b_ims[t];
  }
}

// ---------------- phase 1: E_obs[t][b][:] = embed[b][t][:] @ W_obs[512:,:] ----------------
__global__ __launch_bounds__(256) void k_phase1(
    const float* __restrict__ embed, char* __restrict__ ws) {
  const u16* wobse = (const u16*)(ws + OFF_WOBSET);
  float* eobs = (float*)(ws + OFF_EOBS);
  __shared__ u16 AL[32 * 40];
  const int tid = threadIdx.x;
  const int mb = blockIdx.x;   // 0..1023
  const int w = tid >> 6, l = tid & 63, l15 = l & 15, lk = l >> 4;
  const f32x4 fz = {0.f, 0.f, 0.f, 0.f};
  f32x4 acc[2][8];
  for (int a = 0; a < 2; ++a) for (int f = 0; f < 8; ++f) acc[a][f] = fz;
  const int srow = tid >> 3, sk4 = (tid & 7) * 4;
  const float* abase = embed + (size_t)(mb*32 + srow)*1536 + sk4;
  u16* adst = AL + srow*40 + sk4;
  for (int kk = 0; kk < 48; ++kk) {
    __syncthreads();
    {
      float4 v = *(const float4*)(abase + kk*32);
      uint2 q; q.x = pk2(v.x, v.y); q.y = pk2(v.z, v.w);
      *(uint2*)adst = q;
    }
    __syncthreads();
    bf16x8 af0 = *(const bf16x8*)(AL + l15*40 + lk*8);
    bf16x8 af1 = *(const bf16x8*)(AL + (16 + l15)*40 + lk*8);
    for (int f = 0; f < 8; ++f) {
      bf16x8 bf = *(const bf16x8*)(wobse + bswz(w*8 + f, 48, kk, l));
      acc[0][f] = mfma16(af0, bf, acc[0][f]);
      acc[1][f] = mfma16(af1, bf, acc[1][f]);
    }
  }
  for (int ar = 0; ar < 2; ++ar)
    for (int f = 0; f < 8; ++f) {
      int col = w*128 + f*16 + l15;
      for (int r = 0; r < 4; ++r) {
        int row = mb*32 + ar*16 + lk*4 + r;  // row = b*64 + t
        int bb = row >> 6, tt = row & 63;
        __builtin_nontemporal_store(acc[ar][f][r],
            eobs + ((size_t)tt*512 + bb)*512 + col);
      }
    }
}

// ---------------- px0: init deter0/DF/XD0 + input MLP for t=0 ----------------
__global__ __launch_bounds__(512) void k_px0(
    const float* __restrict__ action, const float* __restrict__ reset,
    const float* __restrict__ g_inp, const float* __restrict__ b_inp,
    char* __restrict__ ws) {
  u16* XX = (u16*)(ws + OFF_XX);
  u16* XD0 = (u16*)(ws + OFF_XD);               // parity 0
  float* DF = (float*)(ws + OFF_DF);
  const u16* WINP = (const u16*)(ws + OFF_WINPT);
  const float* d0 = (const float*)(ws + OFF_D0);
  const float* s0 = (const float*)(ws + OFF_S0);
  __shared__ float D0L[512];
  __shared__ float S0L[32];
  __shared__ float STOL[16*32];
  __shared__ float RLC[16];
  __shared__ u16 CIN[16*72];
  __shared__ float LNB[8][16][2];
  const int tid = threadIdx.x;
  const int w = tid >> 6, l = tid & 63, l15 = l & 15, lk = l >> 4;
  const int r0 = blockIdx.x * 16;
  const f32x4 fz = {0.f,0.f,0.f,0.f};
  if (tid < 512) D0L[tid] = d0[tid];
  if (tid < 32) S0L[tid] = s0[tid];
  if (tid < 16) RLC[tid] = reset[(size_t)(r0 + tid)*NT + 0];
  __syncthreads();
  // init DF/XD0 for this block's 16 rows
  for (int u2 = tid; u2 < 8192; u2 += 512) {
    int rr = u2 >> 9, jj = u2 & 511;
    float v = D0L[jj];
    DF[(size_t)(r0 + rr)*512 + jj] = v;
    XD0[(size_t)(r0 + rr)*512 + jj] = f2b(v);
  }
  if (tid < 512) STOL[tid] = S0L[tid & 31];
  __syncthreads();
  // CIN = [stoch_blend | action*(1-r) | 0pad]; blend is identity at t=0 (carry==s0)
  {
    int rr = tid >> 5, kp = (tid & 31)*2;
    float rv = RLC[rr], onem = 1.f - rv;
    int k1 = kp + 1;
    float v0 = (kp < 32) ? (STOL[rr*32+kp]*onem + S0L[kp]*rv)
             : (kp < 38 ? action[((size_t)(r0+rr)*NT + 0)*6 + kp-32]*onem : 0.f);
    float v1 = (k1 < 32) ? (STOL[rr*32+k1]*onem + S0L[k1]*rv)
             : (k1 < 38 ? action[((size_t)(r0+rr)*NT + 0)*6 + k1-32]*onem : 0.f);
    *(u32*)(CIN + rr*72 + kp) = pk2(v0, v1);
  }
  __syncthreads();
  f32x4 ai[4];
  for (int f = 0; f < 4; ++f) ai[f] = fz;
  for (int kk = 0; kk < 2; ++kk) {
    bf16x8 af = *(const bf16x8*)(CIN + l15*72 + kk*32 + lk*8);
    for (int f = 0; f < 4; ++f) {
      bf16x8 bf = *(const bf16x8*)(WINP + bswz(w*4 + f, 2, kk, l));
      ai[f] = mfma16(af, bf, ai[f]);
    }
  }
  for (int r = 0; r < 4; ++r) {
    float s1 = 0.f, s2 = 0.f;
    for (int f = 0; f < 4; ++f) { float v = ai[f][r]; s1 += v; s2 += v*v; }
    for (int d = 1; d < 16; d <<= 1) { s1 += __shfl_xor(s1, d); s2 += __shfl_xor(s2, d); }
    if (l15 == 0) { LNB[w][lk*4 + r][0] = s1; LNB[w][lk*4 + r][1] = s2; }
  }
  __syncthreads();
  float mr[4], ir[4];
  for (int r = 0; r < 4; ++r) {
    int row = lk*4 + r;
    float S1 = 0.f, S2 = 0.f;
    for (int wv = 0; wv < 8; ++wv) { S1 += LNB[wv][row][0]; S2 += LNB[wv][row][1]; }
    float m = S1 * (1.f/512.f);
    float var = S2 * (1.f/512.f) - m*m;
    mr[r] = m; ir[r] = rsqrtf(var + 1e-3f);
  }
  for (int f = 0; f < 4; ++f) {
    int col = w*64 + f*16 + l15;
    float gg = g_inp[col], bb = b_inp[col];
    for (int r = 0; r < 4; ++r)
      XX[(size_t)(r0 + lk*4 + r)*512 + col] = f2b(siluf((ai[f][r] - mr[r]) * ir[r] * gg + bb));
  }
}

// ---------------- per-step GRU: 256 blocks; block (g,p): 64 rows x 16 cols x 3 gates ----------------
__global__ __launch_bounds__(256) void k_gru(
    const float* __restrict__ reset, float* __restrict__ out,
    char* __restrict__ ws, int t) {
  const u16* WGRU = (const u16*)(ws + OFF_WGRUT);
  const u16* XX = (const u16*)(ws + OFF_XX);
  const u16* XDin = (const u16*)(ws + OFF_XD) + (size_t)(t & 1)*512*512;
  u16* XDout = (u16*)(ws + OFF_XD) + (size_t)((t+1) & 1)*512*512;
  float* DF = (float*)(ws + OFF_DF);
  const float* d0 = (const float*)(ws + OFF_D0);
  __shared__ float D0L[512];
  const int tid = threadIdx.x;
  const int w = tid >> 6, l = tid & 63, l15 = l & 15, lk = l >> 4;
  const int g = blockIdx.x >> 5, p = blockIdx.x & 31;
  const int grow0 = g * 64;
  const int jcol = p*16 + l15;
  const f32x4 fz = {0.f,0.f,0.f,0.f};
  for (int u2 = tid; u2 < 512; u2 += 256) D0L[u2] = d0[u2];
  __syncthreads();
  const int arow = grow0 + w*16;
  const float rl = reset[(size_t)(arow + l15)*NT + t];
  const u16* xrow = XX + (size_t)(arow + l15)*512 + lk*8;
  const u16* drow = XDin + (size_t)(arow + l15)*512 + lk*8;
  f32x4 ag0 = fz, ag1 = fz, ag2 = fz;
  #pragma unroll 4
  for (int kk = 0; kk < 16; ++kk) {
    bf16x8 af = *(const bf16x8*)(xrow + kk*32);
    bf16x8 b0 = *(const bf16x8*)(WGRU + bswz(p,      32, kk, l));
    bf16x8 b1 = *(const bf16x8*)(WGRU + bswz(32 + p, 32, kk, l));
    bf16x8 b2 = *(const bf16x8*)(WGRU + bswz(64 + p, 32, kk, l));
    ag0 = mfma16(af, b0, ag0); ag1 = mfma16(af, b1, ag1); ag2 = mfma16(af, b2, ag2);
  }
  #pragma unroll 4
  for (int kk = 0; kk < 16; ++kk) {
    bf16x8 af = *(const bf16x8*)(drow + kk*32);
    if (rl != 0.f) {
      u16* pp = (u16*)&af;
      for (int i = 0; i < 8; ++i)
        pp[i] = f2b(b2f(pp[i])*(1.f - rl) + D0L[kk*32 + lk*8 + i]*rl);
    }
    bf16x8 b0 = *(const bf16x8*)(WGRU + bswz(p,      32, 16 + kk, l));
    bf16x8 b1 = *(const bf16x8*)(WGRU + bswz(32 + p, 32, 16 + kk, l));
    bf16x8 b2 = *(const bf16x8*)(WGRU + bswz(64 + p, 32, 16 + kk, l));
    ag0 = mfma16(af, b0, ag0); ag1 = mfma16(af, b1, ag1); ag2 = mfma16(af, b2, ag2);
  }
  for (int r = 0; r < 4; ++r) {
    int row = arow + lk*4 + r;
    float rr = reset[(size_t)row*NT + t];
    size_t idx = (size_t)row*512 + jcol;
    float dold = DF[idx];
    if (rr != 0.f) dold = dold*(1.f - rr) + D0L[jcol]*rr;
    float rg_ = sigf(ag0[r]);
    float ca = tanhf(rg_ * ag1[r]);
    float up = sigf(ag2[r] - 1.f);
    float dn = up*ca + (1.f - up)*dold;
    DF[idx] = dn;
    XDout[idx] = f2b(dn);
    out[((size_t)row*NT + t)*704 + 192 + jcol] = dn;
  }
}

// ---------------- per-step OBS: 32 blocks x 512; obs+LN+ostat+sample + next-step input MLP ----------------
__global__ __launch_bounds__(512) void k_obs(
    const float* __restrict__ action, const float* __restrict__ reset,
    const float* __restrict__ g_inp, const float* __restrict__ b_inp,
    const float* __restrict__ g_obs, const float* __restrict__ b_obs,
    const float* __restrict__ b_ostat, const float* __restrict__ npost,
    float* __restrict__ out, char* __restrict__ ws, int t) {
  const u16* WOBSD = (const u16*)(ws + OFF_WOBSDT);
  const u16* WOST  = (const u16*)(ws + OFF_WOSTT);
  const u16* WINP  = (const u16*)(ws + OFF_WINPT);
  const float* eobs = (const float*)(ws + OFF_EOBS);
  const u16* XDn = (const u16*)(ws + OFF_XD) + (size_t)((t+1) & 1)*512*512;
  u16* XX = (u16*)(ws + OFF_XX);
  const float* s0 = (const float*)(ws + OFF_S0);
  __shared__ u16 HLDS[16*520];
  __shared__ float LNB[8][16][2];
  __shared__ float STL[16*64];
  __shared__ float STOL[16*32];
  __shared__ float RLC[16];
  __shared__ u16 CIN[16*72];
  __shared__ float S0L[32];
  const int tid = threadIdx.x;
  const int w = tid >> 6, l = tid & 63, l15 = l & 15, lk = l >> 4;
  const int r0 = blockIdx.x * 16;
  const f32x4 fz = {0.f,0.f,0.f,0.f};
  if (tid < 32) S0L[tid] = s0[tid];
  // ---- obs GEMM: deter_n @ W_obsd + eobs ----
  f32x4 ao[4];
  for (int f = 0; f < 4; ++f) ao[f] = fz;
  const u16* abase = XDn + (size_t)(r0 + l15)*512 + lk*8;
  #pragma unroll 4
  for (int kk = 0; kk < 16; ++kk) {
    bf16x8 af = *(const bf16x8*)(abase + kk*32);
    for (int f = 0; f < 4; ++f) {
      bf16x8 bf = *(const bf16x8*)(WOBSD + bswz(w*4 + f, 16, kk, l));
      ao[f] = mfma16(af, bf, ao[f]);
    }
  }
  for (int f = 0; f < 4; ++f) {
    int col = w*64 + f*16 + l15;
    for (int r = 0; r < 4; ++r)
      ao[f][r] += eobs[((size_t)t*512 + r0 + lk*4 + r)*512 + col];
  }
  for (int r = 0; r < 4; ++r) {
    float s1 = 0.f, s2 = 0.f;
    for (int f = 0; f < 4; ++f) { float v = ao[f][r]; s1 += v; s2 += v*v; }
    for (int d = 1; d < 16; d <<= 1) { s1 += __shfl_xor(s1, d); s2 += __shfl_xor(s2, d); }
    if (l15 == 0) { LNB[w][lk*4 + r][0] = s1; LNB[w][lk*4 + r][1] = s2; }
  }
  __syncthreads();
  {
    float mr[4], ir[4];
    for (int r = 0; r < 4; ++r) {
      int row = lk*4 + r;
      float S1 = 0.f, S2 = 0.f;
      for (int wv = 0; wv < 8; ++wv) { S1 += LNB[wv][row][0]; S2 += LNB[wv][row][1]; }
      float m = S1 * (1.f/512.f);
      float var = S2 * (1.f/512.f) - m*m;
      mr[r] = m; ir[r] = rsqrtf(var + 1e-3f);
    }
    for (int f = 0; f < 4; ++f) {
      int col = w*64 + f*16 + l15;
      float gg = g_obs[col], bb = b_obs[col];
      for (int r = 0; r < 4; ++r)
        HLDS[(lk*4 + r)*520 + col] = f2b(siluf((ao[f][r] - mr[r]) * ir[r] * gg + bb));
    }
  }
  __syncthreads();
  // ---- ostat (waves 0..3) ----
  if (w < 4) {
    f32x4 q = fz;
    #pragma unroll 4
    for (int kk = 0; kk < 16; ++kk) {
      bf16x8 af = *(const bf16x8*)(HLDS + l15*520 + kk*32 + lk*8);
      bf16x8 bf = *(const bf16x8*)(WOST + bswz(w, 16, kk, l));
      q = mfma16(af, bf, q);
    }
    float bia = b_ostat[w*16 + l15];
    for (int r = 0; r < 4; ++r) STL[(lk*4 + r)*64 + w*16 + l15] = q[r] + bia;
  }
  __syncthreads();
  // ---- sample + q outputs ----
  {
    int row = tid >> 5, i = tid & 31;
    float qm = STL[row*64 + i];
    float qs = softplusf(STL[row*64 + 32 + i]) + 0.1f;
    float ns = npost[((size_t)t*512 + r0 + row)*32 + i];
    float qst = qm + qs*ns;
    size_t ob = ((size_t)(r0 + row)*NT + t)*704;
    out[ob + i] = qm;
    out[ob + 32 + i] = qs;
    out[ob + 64 + i] = qst;
    STOL[row*32 + i] = qst;
  }
  __syncthreads();
  // ---- input MLP for step t+1 ----
  if (t < NT - 1) {
    const int tn = t + 1;
    if (tid < 16) RLC[tid] = reset[(size_t)(r0 + tid)*NT + tn];
    __syncthreads();
    {
      int rr = tid >> 5, kp = (tid & 31)*2;
      float rv = RLC[rr], onem = 1.f - rv;
      int k1 = kp + 1;
      float v0 = (kp < 32) ? (STOL[rr*32+kp]*onem + S0L[kp]*rv)
               : (kp < 38 ? action[((size_t)(r0+rr)*NT + tn)*6 + kp-32]*onem : 0.f);
      float v1 = (k1 < 32) ? (STOL[rr*32+k1]*onem + S0L[k1]*rv)
               : (k1 < 38 ? action[((size_t)(r0+rr)*NT + tn)*6 + k1-32]*onem : 0.f);
      *(u32*)(CIN + rr*72 + kp) = pk2(v0, v1);
    }
    __syncthreads();
    f32x4 ai[4];
    for (int f = 0; f < 4; ++f) ai[f] = fz;
    for (int kk = 0; kk < 2; ++kk) {
      bf16x8 af = *(const bf16x8*)(CIN + l15*72 + kk*32 + lk*8);
      for (int f = 0; f < 4; ++f) {
        bf16x8 bf = *(const bf16x8*)(WINP + bswz(w*4 + f, 2, kk, l));
        ai[f] = mfma16(af, bf, ai[f]);
      }
    }
    for (int r = 0; r < 4; ++r) {
      float s1 = 0.f, s2 = 0.f;
      for (int f = 0; f < 4; ++f) { float v = ai[f][r]; s1 += v; s2 += v*v; }
      for (int d = 1; d < 16; d <<= 1) { s1 += __shfl_xor(s1, d); s2 += __shfl_xor(s2, d); }
      if (l15 == 0) { LNB[w][lk*4 + r][0] = s1; LNB[w][lk*4 + r][1] = s2; }
    }
    __syncthreads();
    float mr[4], ir[4];
    for (int r = 0; r < 4; ++r) {
      int row = lk*4 + r;
      float S1 = 0.f, S2 = 0.f;
      for (int wv = 0; wv < 8; ++wv) { S1 += LNB[wv][row][0]; S2 += LNB[wv][row][1]; }
      float m = S1 * (1.f/512.f);
      float var = S2 * (1.f/512.f) - m*m;
      mr[r] = m; ir[r] = rsqrtf(var + 1e-3f);
    }
    for (int f = 0; f < 4; ++f) {
      int col = w*64 + f*16 + l15;
      float gg = g_inp[col], bb = b_inp[col];
      for (int r = 0; r < 4; ++r)
        XX[(size_t)(r0 + lk*4 + r)*512 + col] = f2b(siluf((ai[f][r] - mr[r]) * ir[r] * gg + bb));
    }
  }
}

// ---------------- post: prior branch for all (b,t) ----------------
__global__ __launch_bounds__(256) void k_p3(
    const float* __restrict__ g_img, const float* __restrict__ b_img,
    const float* __restrict__ b_ims, const float* __restrict__ nprior,
    float* __restrict__ out, char* __restrict__ ws) {
  const u16* wimgT = (const u16*)(ws + OFF_WIMGT);
  const u16* wimsT = (const u16*)(ws + OFF_WIMST);
  __shared__ u16 AL[32 * 40];
  __shared__ u16 HL[32 * 520];
  __shared__ float LNB[4][32][2];
  __shared__ float STL[32 * 64];
  const int tid = threadIdx.x;
  const int mb = blockIdx.x;   // 0..1023
  const int w = tid >> 6, l = tid & 63, l15 = l & 15, lk = l >> 4;
  const f32x4 fz = {0.f,0.f,0.f,0.f};
  f32x4 acc[2][8];
  for (int rb = 0; rb < 2; ++rb) for (int f = 0; f < 8; ++f) acc[rb][f] = fz;
  const int srow = tid >> 3, sko = (tid & 7) * 4;
  const float* sbase = out + (size_t)(mb*32 + srow)*704 + 192 + sko;  // deter_n
  u16* sdst = AL + srow*40 + sko;
  for (int kk = 0; kk < 16; ++kk) {
    __syncthreads();
    {
      float4 v = *(const float4*)(sbase + kk*32);
      uint2 q; q.x = pk2(v.x, v.y); q.y = pk2(v.z, v.w);
      *(uint2*)sdst = q;
    }
    __syncthreads();
    bf16x8 af0 = *(const bf16x8*)(AL + l15*40 + lk*8);
    bf16x8 af1 = *(const bf16x8*)(AL + (16 + l15)*40 + lk*8);
    for (int f = 0; f < 8; ++f) {
      bf16x8 bf = *(const bf16x8*)(wimgT + bswz(w*8 + f, 16, kk, l));
      acc[0][f] = mfma16(af0, bf, acc[0][f]);
      acc[1][f] = mfma16(af1, bf, acc[1][f]);
    }
  }
  for (int rb = 0; rb < 2; ++rb) {
    for (int r = 0; r < 4; ++r) {
      float s1 = 0.f, s2 = 0.f;
      for (int f = 0; f < 8; ++f) { float v = acc[rb][f][r]; s1 += v; s2 += v*v; }
      for (int d = 1; d < 16; d <<= 1) { s1 += __shfl_xor(s1, d); s2 += __shfl_xor(s2, d); }
      if (l15 == 0) { LNB[w][rb*16 + lk*4 + r][0] = s1; LNB[w][rb*16 + lk*4 + r][1] = s2; }
    }
  }
  __syncthreads();
  for (int rb = 0; rb < 2; ++rb) {
    float mr[4], ir[4];
    for (int r = 0; r < 4; ++r) {
      int row = rb*16 + lk*4 + r;
      float S1 = LNB[0][row][0] + LNB[1][row][0] + LNB[2][row][0] + LNB[3][row][0];
      float S2 = LNB[0][row][1] + LNB[1][row][1] + LNB[2][row][1] + LNB[3][row][1];
      float m = S1 * (1.f/512.f);
      float var = S2 * (1.f/512.f) - m*m;
      mr[r] = m; ir[r] = rsqrtf(var + 1e-3f);
    }
    for (int f = 0; f < 8; ++f) {
      int col = w*128 + f*16 + l15;
      float gg = g_img[col], bb = b_img[col];
      for (int r = 0; r < 4; ++r) {
        float v = siluf((acc[rb][f][r] - mr[r]) * ir[r] * gg + bb);
        HL[(rb*16 + lk*4 + r)*520 + col] = f2b(v);
      }
    }
  }
  __syncthreads();
  f32x4 q0 = fz, q1 = fz;
  for (int kk = 0; kk < 16; ++kk) {
    bf16x8 bf = *(const bf16x8*)(wimsT + bswz(w, 16, kk, l));
    bf16x8 af0 = *(const bf16x8*)(HL + l15*520 + kk*32 + lk*8);
    bf16x8 af1 = *(const bf16x8*)(HL + (16 + l15)*520 + kk*32 + lk*8);
    q0 = mfma16(af0, bf, q0);
    q1 = mfma16(af1, bf, q1);
  }
  float bia = b_ims[w*16 + l15];
  for (int r = 0; r < 4; ++r) {
    STL[(lk*4 + r)*64 + w*16 + l15] = q0[r] + bia;
    STL[(16 + lk*4 + r)*64 + w*16 + l15] = q1[r] + bia;
  }
  __syncthreads();
  for (int it = tid; it < 1024; it += 256) {
    int row = it >> 5, i = it & 31;
    int grow = mb*32 + row;
    int bb = grow >> 6, tt = grow & 63;
    float pm = STL[row*64 + i];
    float ps = softplusf(STL[row*64 + 32 + i]) + 0.1f;
    float nr = nprior[((size_t)tt*512 + bb)*32 + i];
    float pst = pm + ps*nr;
    size_t ob = (size_t)grow*704;
    out[ob + 96 + i] = pm;
    out[ob + 128 + i] = ps;
    out[ob + 160 + i] = pst;
  }
}

extern "C" void kernel_launch(void* const* d_in, const int* in_sizes, int n_in,
                              void* d_out, int out_size, void* d_ws, size_t ws_size,
                              hipStream_t stream) {
  const float* embed   = (const float*)d_in[0];
  const float* action  = (const float*)d_in[1];
  const float* reset   = (const float*)d_in[2];
  const float* npost   = (const float*)d_in[3];
  const float* nprior  = (const float*)d_in[4];
  const float* W_inp   = (const float*)d_in[5];
  const float* g_inp   = (const float*)d_in[6];
  const float* b_inp   = (const float*)d_in[7];
  const float* W_gru   = (const float*)d_in[8];
  const float* W_img   = (const float*)d_in[9];
  const float* g_img   = (const float*)d_in[10];
  const float* b_img   = (const float*)d_in[11];
  const float* W_obs   = (const float*)d_in[12];
  const float* g_obs   = (const float*)d_in[13];
  const float* b_obs   = (const float*)d_in[14];
  const float* W_ims   = (const float*)d_in[15];
  const float* b_ims   = (const float*)d_in[16];
  const float* W_ostat = (const float*)d_in[17];
  const float* b_ostat = (const float*)d_in[18];
  const float* W_init  = (const float*)d_in[19];
  float* out = (float*)d_out;
  char* ws = (char*)d_ws;
  if (ws_size < WS_NEED) return;

  k_convert<<<11648, 256, 0, stream>>>(W_inp, W_gru, W_img, W_obs, W_ims, W_ostat, ws);
  k_init_a<<<1, 256, 0, stream>>>(W_init, W_img, g_img, b_img, W_ims, b_ims, ws);
  k_phase1<<<1024, 256, 0, stream>>>(embed, ws);
  k_px0<<<32, 512, 0, stream>>>(action, reset, g_inp, b_inp, ws);
  for (int t = 0; t < NT; ++t) {
    k_gru<<<256, 256, 0, stream>>>(reset, out, ws, t);
    k_obs<<<32, 512, 0, stream>>>(action, reset, g_inp, b_inp, g_obs, b_obs,
                                  b_ostat, npost, out, ws, t);
  }
  k_p3<<<1024, 256, 0, stream>>>(g_img, b_img, b_ims, nprior, out, ws);
}

// Round 7
// 2268.966 us; speedup vs baseline: 6.2320x; 1.1223x over previous
//
#include <hip/hip_runtime.h>
#include <stdint.h>

typedef unsigned short u16;
typedef unsigned int u32;
typedef __attribute__((ext_vector_type(8))) short bf16x8;
typedef __attribute__((ext_vector_type(4))) float f32x4;

#define DEV __device__ __forceinline__

#define NB 512   // batch
#define NT 64    // time
#define NE 1536  // embed
#define NH 512   // hid == deter
#define NS 32    // stoch

// ---- workspace layout (bytes) ----
static constexpr size_t OFF_EOBS   = 0;                                  // [T][B][512] f32 = 64MB
static constexpr size_t OFF_XX     = OFF_EOBS + (size_t)NT*NB*512*4;     // [512][512] bf16 (x)
static constexpr size_t OFF_XD     = OFF_XX + (size_t)512*512*2;         // [2][512][512] bf16 deter dbuf
static constexpr size_t OFF_DF     = OFF_XD + (size_t)2*512*512*2;       // [512][512] f32 deter carry
static constexpr size_t OFF_ACC    = OFF_DF + (size_t)512*512*4;         // [512][512] f32 obs pre-LN
static constexpr size_t OFF_LNP    = OFF_ACC + (size_t)512*512*4;        // [512][8][2] f32 LN partials
static constexpr size_t OFF_D0     = OFF_LNP + (size_t)512*8*2*4;        // [512] f32
static constexpr size_t OFF_S0     = OFF_D0 + 512*4;                     // [32] f32 (pad 256)
static constexpr size_t OFF_WINPT  = OFF_S0 + 256;                       // 32cg x 2kk swizzled
static constexpr size_t OFF_WGRUT  = OFF_WINPT + (size_t)512*64*2;       // 96cg x 32kk
static constexpr size_t OFF_WIMGT  = OFF_WGRUT + (size_t)1536*1024*2;    // 32cg x 16kk
static constexpr size_t OFF_WOBSDT = OFF_WIMGT + (size_t)512*512*2;      // 32cg x 16kk
static constexpr size_t OFF_WOBSET = OFF_WOBSDT + (size_t)512*512*2;     // 32cg x 48kk
static constexpr size_t OFF_WIMST  = OFF_WOBSET + (size_t)512*1536*2;    // 4cg x 16kk
static constexpr size_t OFF_WOSTT  = OFF_WIMST + (size_t)64*512*2;       // 4cg x 16kk
static constexpr size_t WS_NEED    = OFF_WOSTT + (size_t)64*512*2;       // ~73.2 MB

DEV u16 f2b(float f) {
  u32 u = __builtin_bit_cast(u32, f);
  u32 r = (u + 0x7FFFu + ((u >> 16) & 1u)) >> 16;
  return (u16)r;
}
DEV float b2f(u16 h) { u32 u = (u32)h << 16; return __builtin_bit_cast(float, u); }
DEV u32 pk2(float a, float b) { return (u32)f2b(a) | ((u32)f2b(b) << 16); }
DEV float sigf(float x) { return 1.f / (1.f + __expf(-x)); }
DEV float siluf(float x) { return x * sigf(x); }
DEV float softplusf(float x) { return (x > 20.f) ? x : log1pf(__expf(x)); }
DEV f32x4 mfma16(bf16x8 a, bf16x8 b, f32x4 c) {
  return __builtin_amdgcn_mfma_f32_16x16x32_bf16(a, b, c, 0, 0, 0);
}
// swizzled B-fragment layout: element i of (colgrp,kk,lane) group =
//   W[kk*32 + (lane>>4)*8 + i][colgrp*16 + (lane&15)]
DEV size_t bswz(int colgrp, int kkmax, int kk, int lane) {
  return (((size_t)colgrp * kkmax + kk) * 64 + lane) * 8;
}

// ---------------- weight conversion: f32 -> bf16, MFMA-fragment-swizzled ----------------
__global__ __launch_bounds__(256) void k_convert(
    const float* __restrict__ W_inp, const float* __restrict__ W_gru,
    const float* __restrict__ W_img, const float* __restrict__ W_obs,
    const float* __restrict__ W_ims, const float* __restrict__ W_ostat,
    char* __restrict__ ws) {
  u16* winpT  = (u16*)(ws + OFF_WINPT);
  u16* wgruT  = (u16*)(ws + OFF_WGRUT);
  u16* wimgT  = (u16*)(ws + OFF_WIMGT);
  u16* wobsdT = (u16*)(ws + OFF_WOBSDT);
  u16* wobseT = (u16*)(ws + OFF_WOBSET);
  u16* wimsT  = (u16*)(ws + OFF_WIMST);
  u16* wostT  = (u16*)(ws + OFF_WOSTT);
  int o = blockIdx.x * 256 + threadIdx.x;
  if (o < 32768) {  // winp: K=64(pad from 38), N=512, KK=2
    int i = o & 7, lane = (o >> 3) & 63, rem = o >> 9;
    int kk = rem & 1, cg = rem >> 1;
    int col = cg*16 + (lane & 15), k = kk*32 + (lane >> 4)*8 + i;
    winpT[o] = (k < 38) ? f2b(W_inp[k*512 + col]) : (u16)0;
    return;
  }
  o -= 32768;
  if (o < 1572864) {  // wgru: K=1024, N=1536, KK=32
    int i = o & 7, lane = (o >> 3) & 63, rem = o >> 9;
    int kk = rem & 31, cg = rem >> 5;
    int col = cg*16 + (lane & 15), k = kk*32 + (lane >> 4)*8 + i;
    wgruT[o] = f2b(W_gru[(size_t)k*1536 + col]);
    return;
  }
  o -= 1572864;
  if (o < 262144) {  // wimg
    int i = o & 7, lane = (o >> 3) & 63, rem = o >> 9;
    int kk = rem & 15, cg = rem >> 4;
    int col = cg*16 + (lane & 15), k = kk*32 + (lane >> 4)*8 + i;
    wimgT[o] = f2b(W_img[k*512 + col]);
    return;
  }
  o -= 262144;
  if (o < 262144) {  // wobsd
    int i = o & 7, lane = (o >> 3) & 63, rem = o >> 9;
    int kk = rem & 15, cg = rem >> 4;
    int col = cg*16 + (lane & 15), k = kk*32 + (lane >> 4)*8 + i;
    wobsdT[o] = f2b(W_obs[k*512 + col]);
    return;
  }
  o -= 262144;
  if (o < 786432) {  // wobse
    int i = o & 7, lane = (o >> 3) & 63, rem = o >> 9;
    int kk = rem % 48, cg = rem / 48;
    int col = cg*16 + (lane & 15), k = kk*32 + (lane >> 4)*8 + i;
    wobseT[o] = f2b(W_obs[(size_t)(512 + k)*512 + col]);
    return;
  }
  o -= 786432;
  if (o < 32768) {  // wims
    int i = o & 7, lane = (o >> 3) & 63, rem = o >> 9;
    int kk = rem & 15, cg = rem >> 4;
    int col = cg*16 + (lane & 15), k = kk*32 + (lane >> 4)*8 + i;
    wimsT[o] = f2b(W_ims[k*64 + col]);
    return;
  }
  o -= 32768;
  {  // wost
    int i = o & 7, lane = (o >> 3) & 63, rem = o >> 9;
    int kk = rem & 15, cg = rem >> 4;
    int col = cg*16 + (lane & 15), k = kk*32 + (lane >> 4)*8 + i;
    wostT[o] = f2b(W_ostat[k*64 + col]);
  }
}

// ---------------- initial state ----------------
__global__ __launch_bounds__(256) void k_init_a(
    const float* __restrict__ W_init, const float* __restrict__ W_img,
    const float* __restrict__ g_img, const float* __restrict__ b_img,
    const float* __restrict__ W_ims, const float* __restrict__ b_ims,
    char* __restrict__ ws) {
  __shared__ float DL[512];
  __shared__ float HL[512];
  __shared__ float RED[256];
  float* d0 = (float*)(ws + OFF_D0);
  float* s0 = (float*)(ws + OFF_S0);
  const int t = threadIdx.x;
  for (int j = t; j < 512; j += 256) { float v = tanhf(W_init[j]); DL[j] = v; d0[j] = v; }
  __syncthreads();
  float pre0 = 0.f, pre1 = 0.f;
  for (int k = 0; k < 512; ++k) {
    float dv = DL[k];
    pre0 += dv * W_img[k*512 + t];
    pre1 += dv * W_img[k*512 + t + 256];
  }
  RED[t] = pre0 + pre1;
  __syncthreads();
  for (int s = 128; s > 0; s >>= 1) { if (t < s) RED[t] += RED[t + s]; __syncthreads(); }
  float m = RED[0] * (1.f/512.f);
  __syncthreads();
  RED[t] = pre0*pre0 + pre1*pre1;
  __syncthreads();
  for (int s = 128; s > 0; s >>= 1) { if (t < s) RED[t] += RED[t + s]; __syncthreads(); }
  float var = RED[0] * (1.f/512.f) - m*m;
  float inv = rsqrtf(var + 1e-3f);
  HL[t]       = siluf((pre0 - m)*inv*g_img[t] + b_img[t]);
  HL[t + 256] = siluf((pre1 - m)*inv*g_img[t+256] + b_img[t+256]);
  __syncthreads();
  if (t < 32) {
    float s = 0.f;
    for (int k = 0; k < 512; ++k) s += HL[k] * W_ims[k*64 + t];
    s0[t] = s + b_ims[t];
  }
}

// ---------------- phase 1: E_obs = embed @ W_obs[512:,:], double-buffered staging ----------------
__global__ __launch_bounds__(256) void k_phase1(
    const float* __restrict__ embed, char* __restrict__ ws) {
  const u16* wobse = (const u16*)(ws + OFF_WOBSET);
  float* eobs = (float*)(ws + OFF_EOBS);
  __shared__ u16 AL[2][32 * 40];
  const int tid = threadIdx.x;
  const int mb = blockIdx.x;   // 0..1023
  const int w = tid >> 6, l = tid & 63, l15 = l & 15, lk = l >> 4;
  const f32x4 fz = {0.f, 0.f, 0.f, 0.f};
  f32x4 acc[2][8];
  for (int a = 0; a < 2; ++a) for (int f = 0; f < 8; ++f) acc[a][f] = fz;
  const int srow = tid >> 3, sk4 = (tid & 7) * 4;
  const float* abase = embed + (size_t)(mb*32 + srow)*1536 + sk4;
  const int aoff = srow*40 + sk4;
  {  // prologue: kk=0 into buf0
    float4 v = *(const float4*)(abase);
    uint2 q; q.x = pk2(v.x, v.y); q.y = pk2(v.z, v.w);
    *(uint2*)(AL[0] + aoff) = q;
  }
  float4 vp = *(const float4*)(abase + 32);   // prefetch kk=1
  __syncthreads();
  for (int kk = 0; kk < 48; ++kk) {
    if (kk < 47) {   // write next buffer (not being read this iter)
      uint2 q; q.x = pk2(vp.x, vp.y); q.y = pk2(vp.z, vp.w);
      *(uint2*)(AL[(kk+1)&1] + aoff) = q;
    }
    if (kk < 46) vp = *(const float4*)(abase + (kk+2)*32);
    const u16* ALc = AL[kk&1];
    bf16x8 af0 = *(const bf16x8*)(ALc + l15*40 + lk*8);
    bf16x8 af1 = *(const bf16x8*)(ALc + (16 + l15)*40 + lk*8);
    for (int f = 0; f < 8; ++f) {
      bf16x8 bf = *(const bf16x8*)(wobse + bswz(w*8 + f, 48, kk, l));
      acc[0][f] = mfma16(af0, bf, acc[0][f]);
      acc[1][f] = mfma16(af1, bf, acc[1][f]);
    }
    __syncthreads();
  }
  for (int ar = 0; ar < 2; ++ar)
    for (int f = 0; f < 8; ++f) {
      int col = w*128 + f*16 + l15;
      for (int r = 0; r < 4; ++r) {
        int row = mb*32 + ar*16 + lk*4 + r;  // row = b*64 + t
        int bb = row >> 6, tt = row & 63;
        __builtin_nontemporal_store(acc[ar][f][r],
            eobs + ((size_t)tt*512 + bb)*512 + col);
      }
    }
}

// ---------------- px0: init deter0/DF/XD0 + input MLP for t=0 ----------------
__global__ __launch_bounds__(512) void k_px0(
    const float* __restrict__ action, const float* __restrict__ reset,
    const float* __restrict__ g_inp, const float* __restrict__ b_inp,
    char* __restrict__ ws) {
  u16* XX = (u16*)(ws + OFF_XX);
  u16* XD0 = (u16*)(ws + OFF_XD);               // parity 0
  float* DF = (float*)(ws + OFF_DF);
  const u16* WINP = (const u16*)(ws + OFF_WINPT);
  const float* d0 = (const float*)(ws + OFF_D0);
  const float* s0 = (const float*)(ws + OFF_S0);
  __shared__ float D0L[512];
  __shared__ float S0L[32];
  __shared__ float STOL[16*32];
  __shared__ float RLC[16];
  __shared__ u16 CIN[16*72];
  __shared__ float LNB[8][16][2];
  const int tid = threadIdx.x;
  const int w = tid >> 6, l = tid & 63, l15 = l & 15, lk = l >> 4;
  const int r0 = blockIdx.x * 16;
  const f32x4 fz = {0.f,0.f,0.f,0.f};
  if (tid < 512) D0L[tid] = d0[tid];
  if (tid < 32) S0L[tid] = s0[tid];
  if (tid < 16) RLC[tid] = reset[(size_t)(r0 + tid)*NT + 0];
  __syncthreads();
  for (int u2 = tid; u2 < 8192; u2 += 512) {
    int rr = u2 >> 9, jj = u2 & 511;
    float v = D0L[jj];
    DF[(size_t)(r0 + rr)*512 + jj] = v;
    XD0[(size_t)(r0 + rr)*512 + jj] = f2b(v);
  }
  if (tid < 512) STOL[tid] = S0L[tid & 31];
  __syncthreads();
  {
    int rr = tid >> 5, kp = (tid & 31)*2;
    float rv = RLC[rr], onem = 1.f - rv;
    int k1 = kp + 1;
    float v0 = (kp < 32) ? (STOL[rr*32+kp]*onem + S0L[kp]*rv)
             : (kp < 38 ? action[((size_t)(r0+rr)*NT + 0)*6 + kp-32]*onem : 0.f);
    float v1 = (k1 < 32) ? (STOL[rr*32+k1]*onem + S0L[k1]*rv)
             : (k1 < 38 ? action[((size_t)(r0+rr)*NT + 0)*6 + k1-32]*onem : 0.f);
    *(u32*)(CIN + rr*72 + kp) = pk2(v0, v1);
  }
  __syncthreads();
  f32x4 ai[4];
  for (int f = 0; f < 4; ++f) ai[f] = fz;
  for (int kk = 0; kk < 2; ++kk) {
    bf16x8 af = *(const bf16x8*)(CIN + l15*72 + kk*32 + lk*8);
    for (int f = 0; f < 4; ++f) {
      bf16x8 bf = *(const bf16x8*)(WINP + bswz(w*4 + f, 2, kk, l));
      ai[f] = mfma16(af, bf, ai[f]);
    }
  }
  for (int r = 0; r < 4; ++r) {
    float s1 = 0.f, s2 = 0.f;
    for (int f = 0; f < 4; ++f) { float v = ai[f][r]; s1 += v; s2 += v*v; }
    for (int d = 1; d < 16; d <<= 1) { s1 += __shfl_xor(s1, d); s2 += __shfl_xor(s2, d); }
    if (l15 == 0) { LNB[w][lk*4 + r][0] = s1; LNB[w][lk*4 + r][1] = s2; }
  }
  __syncthreads();
  float mr[4], ir[4];
  for (int r = 0; r < 4; ++r) {
    int row = lk*4 + r;
    float S1 = 0.f, S2 = 0.f;
    for (int wv = 0; wv < 8; ++wv) { S1 += LNB[wv][row][0]; S2 += LNB[wv][row][1]; }
    float m = S1 * (1.f/512.f);
    float var = S2 * (1.f/512.f) - m*m;
    mr[r] = m; ir[r] = rsqrtf(var + 1e-3f);
  }
  for (int f = 0; f < 4; ++f) {
    int col = w*64 + f*16 + l15;
    float gg = g_inp[col], bb = b_inp[col];
    for (int r = 0; r < 4; ++r)
      XX[(size_t)(r0 + lk*4 + r)*512 + col] = f2b(siluf((ai[f][r] - mr[r]) * ir[r] * gg + bb));
  }
}

// ---------------- per-step GRU: 256 blocks; block (g,p): 64 rows x 16 cols x 3 gates ----------------
__global__ __launch_bounds__(256) void k_gru(
    const float* __restrict__ reset, float* __restrict__ out,
    char* __restrict__ ws, int t) {
  const u16* WGRU = (const u16*)(ws + OFF_WGRUT);
  const u16* XX = (const u16*)(ws + OFF_XX);
  const u16* XDin = (const u16*)(ws + OFF_XD) + (size_t)(t & 1)*512*512;
  u16* XDout = (u16*)(ws + OFF_XD) + (size_t)((t+1) & 1)*512*512;
  float* DF = (float*)(ws + OFF_DF);
  const float* d0 = (const float*)(ws + OFF_D0);
  __shared__ float D0L[512];
  __shared__ float RL[64];
  const int tid = threadIdx.x;
  const int w = tid >> 6, l = tid & 63, l15 = l & 15, lk = l >> 4;
  const int g = blockIdx.x >> 5, p = blockIdx.x & 31;
  const int grow0 = g * 64;
  const int jcol = p*16 + l15;
  const f32x4 fz = {0.f,0.f,0.f,0.f};
  if (tid < 64) RL[tid] = reset[(size_t)(grow0 + tid)*NT + t];
  for (int u2 = tid; u2 < 512; u2 += 256) D0L[u2] = d0[u2];
  __syncthreads();
  const int arow = grow0 + w*16;
  const float rl = RL[w*16 + l15];
  const u16* xrow = XX + (size_t)(arow + l15)*512 + lk*8;
  const u16* drow = XDin + (size_t)(arow + l15)*512 + lk*8;
  f32x4 ag0 = fz, ag1 = fz, ag2 = fz;
  #pragma unroll 4
  for (int kk = 0; kk < 16; ++kk) {
    bf16x8 af = *(const bf16x8*)(xrow + kk*32);
    bf16x8 b0 = *(const bf16x8*)(WGRU + bswz(p,      32, kk, l));
    bf16x8 b1 = *(const bf16x8*)(WGRU + bswz(32 + p, 32, kk, l));
    bf16x8 b2 = *(const bf16x8*)(WGRU + bswz(64 + p, 32, kk, l));
    ag0 = mfma16(af, b0, ag0); ag1 = mfma16(af, b1, ag1); ag2 = mfma16(af, b2, ag2);
  }
  #pragma unroll 4
  for (int kk = 0; kk < 16; ++kk) {
    bf16x8 af = *(const bf16x8*)(drow + kk*32);
    if (rl != 0.f) {
      u16* pp = (u16*)&af;
      for (int i = 0; i < 8; ++i)
        pp[i] = f2b(b2f(pp[i])*(1.f - rl) + D0L[kk*32 + lk*8 + i]*rl);
    }
    bf16x8 b0 = *(const bf16x8*)(WGRU + bswz(p,      32, 16 + kk, l));
    bf16x8 b1 = *(const bf16x8*)(WGRU + bswz(32 + p, 32, 16 + kk, l));
    bf16x8 b2 = *(const bf16x8*)(WGRU + bswz(64 + p, 32, 16 + kk, l));
    ag0 = mfma16(af, b0, ag0); ag1 = mfma16(af, b1, ag1); ag2 = mfma16(af, b2, ag2);
  }
  for (int r = 0; r < 4; ++r) {
    int row = arow + lk*4 + r;
    float rr = RL[w*16 + lk*4 + r];
    size_t idx = (size_t)row*512 + jcol;
    float dold = DF[idx];
    if (rr != 0.f) dold = dold*(1.f - rr) + D0L[jcol]*rr;
    float rg_ = sigf(ag0[r]);
    float ca = tanhf(rg_ * ag1[r]);
    float up = sigf(ag2[r] - 1.f);
    float dn = up*ca + (1.f - up)*dold;
    DF[idx] = dn;
    XDout[idx] = f2b(dn);
    out[((size_t)row*NT + t)*704 + 192 + jcol] = dn;
  }
}

// ---------------- per-step OBS-A: 256 blocks; block (rg,oc): 16 rows x 64 cols obs GEMM ----------------
__global__ __launch_bounds__(256) void k_obsA(char* __restrict__ ws, int t) {
  const u16* WOBSD = (const u16*)(ws + OFF_WOBSDT);
  const float* eobs = (const float*)(ws + OFF_EOBS);
  const u16* XDn = (const u16*)(ws + OFF_XD) + (size_t)((t+1) & 1)*512*512;
  float* ACC = (float*)(ws + OFF_ACC);
  float* LNP = (float*)(ws + OFF_LNP);
  __shared__ float LNB[4][16][2];
  const int tid = threadIdx.x;
  const int w = tid >> 6, l = tid & 63, l15 = l & 15, lk = l >> 4;
  const int rg = blockIdx.x >> 3, oc = blockIdx.x & 7;  // bid%8=oc -> W slice XCD-affine
  const int cg = oc*4 + w;
  const f32x4 fz = {0.f,0.f,0.f,0.f};
  f32x4 ao = fz;
  const u16* abase = XDn + (size_t)(rg*16 + l15)*512 + lk*8;
  #pragma unroll 4
  for (int kk = 0; kk < 16; ++kk) {
    bf16x8 af = *(const bf16x8*)(abase + kk*32);
    bf16x8 bf = *(const bf16x8*)(WOBSD + bswz(cg, 16, kk, l));
    ao = mfma16(af, bf, ao);
  }
  const int col = cg*16 + l15;
  float vs[4];
  for (int r = 0; r < 4; ++r) {
    int row = rg*16 + lk*4 + r;
    float v = ao[r] + eobs[((size_t)t*512 + row)*512 + col];
    vs[r] = v;
    ACC[(size_t)row*512 + col] = v;
  }
  for (int r = 0; r < 4; ++r) {
    float s1 = vs[r], s2 = vs[r]*vs[r];
    for (int d = 1; d < 16; d <<= 1) { s1 += __shfl_xor(s1, d); s2 += __shfl_xor(s2, d); }
    if (l15 == 0) { LNB[w][lk*4 + r][0] = s1; LNB[w][lk*4 + r][1] = s2; }
  }
  __syncthreads();
  if (tid < 16) {
    float S1 = LNB[0][tid][0]+LNB[1][tid][0]+LNB[2][tid][0]+LNB[3][tid][0];
    float S2 = LNB[0][tid][1]+LNB[1][tid][1]+LNB[2][tid][1]+LNB[3][tid][1];
    LNP[((size_t)(rg*16 + tid)*8 + oc)*2]     = S1;
    LNP[((size_t)(rg*16 + tid)*8 + oc)*2 + 1] = S2;
  }
}

// ---------------- per-step OBS-B: 32 blocks x 512; LN finish + h + ostat + sample + px(t+1) ----------------
__global__ __launch_bounds__(512) void k_obsB(
    const float* __restrict__ action, const float* __restrict__ reset,
    const float* __restrict__ g_inp, const float* __restrict__ b_inp,
    const float* __restrict__ g_obs, const float* __restrict__ b_obs,
    const float* __restrict__ b_ostat, const float* __restrict__ npost,
    float* __restrict__ out, char* __restrict__ ws, int t) {
  const u16* WOST = (const u16*)(ws + OFF_WOSTT);
  const u16* WINP = (const u16*)(ws + OFF_WINPT);
  const float* ACC = (const float*)(ws + OFF_ACC);
  const float* LNP = (const float*)(ws + OFF_LNP);
  u16* XX = (u16*)(ws + OFF_XX);
  const float* s0 = (const float*)(ws + OFF_S0);
  __shared__ u16 HLDS[16*520];
  __shared__ float LNB[8][16][2];
  __shared__ float STL[16*64];
  __shared__ float STOL[16*32];
  __shared__ float RLC[16];
  __shared__ u16 CIN[16*72];
  __shared__ float S0L[32];
  __shared__ float MIV[16][2];
  const int tid = threadIdx.x;
  const int w = tid >> 6, l = tid & 63, l15 = l & 15, lk = l >> 4;
  const int r0 = blockIdx.x * 16;
  const f32x4 fz = {0.f,0.f,0.f,0.f};
  if (tid < 32) S0L[tid] = s0[tid];
  if (tid < 16) {   // combine LN partials over the 8 col-chunks
    float S1 = 0.f, S2 = 0.f;
    for (int o = 0; o < 8; ++o) {
      S1 += LNP[((size_t)(r0 + tid)*8 + o)*2];
      S2 += LNP[((size_t)(r0 + tid)*8 + o)*2 + 1];
    }
    float m = S1 * (1.f/512.f);
    float var = S2 * (1.f/512.f) - m*m;
    MIV[tid][0] = m; MIV[tid][1] = rsqrtf(var + 1e-3f);
  }
  __syncthreads();
  {  // h = silu(LN(ACC)) -> HLDS (each thread: 16 cols of one row, coalesced float4)
    int row = tid >> 5, c0 = (tid & 31)*16;
    float m = MIV[row][0], iv = MIV[row][1];
    const float4* a4 = (const float4*)(ACC + (size_t)(r0+row)*512 + c0);
    const float4* g4 = (const float4*)(g_obs + c0);
    const float4* b4 = (const float4*)(b_obs + c0);
    u16* hrow = HLDS + row*520 + c0;
    for (int q4 = 0; q4 < 4; ++q4) {
      float4 av = a4[q4];
      float4 gv = g4[q4];
      float4 bv = b4[q4];
      float v0 = siluf((av.x - m)*iv*gv.x + bv.x);
      float v1 = siluf((av.y - m)*iv*gv.y + bv.y);
      float v2 = siluf((av.z - m)*iv*gv.z + bv.z);
      float v3 = siluf((av.w - m)*iv*gv.w + bv.w);
      uint2 q; q.x = pk2(v0, v1); q.y = pk2(v2, v3);
      *(uint2*)(hrow + q4*4) = q;
    }
  }
  __syncthreads();
  if (w < 4) {  // ostat
    f32x4 q = fz;
    #pragma unroll 4
    for (int kk = 0; kk < 16; ++kk) {
      bf16x8 af = *(const bf16x8*)(HLDS + l15*520 + kk*32 + lk*8);
      bf16x8 bf = *(const bf16x8*)(WOST + bswz(w, 16, kk, l));
      q = mfma16(af, bf, q);
    }
    float bia = b_ostat[w*16 + l15];
    for (int r = 0; r < 4; ++r) STL[(lk*4 + r)*64 + w*16 + l15] = q[r] + bia;
  }
  __syncthreads();
  {  // sample + q outputs
    int row = tid >> 5, i = tid & 31;
    float qm = STL[row*64 + i];
    float qs = softplusf(STL[row*64 + 32 + i]) + 0.1f;
    float ns = npost[((size_t)t*512 + r0 + row)*32 + i];
    float qst = qm + qs*ns;
    size_t ob = ((size_t)(r0 + row)*NT + t)*704;
    out[ob + i] = qm;
    out[ob + 32 + i] = qs;
    out[ob + 64 + i] = qst;
    STOL[row*32 + i] = qst;
  }
  __syncthreads();
  if (t < NT - 1) {  // input MLP for step t+1
    const int tn = t + 1;
    if (tid < 16) RLC[tid] = reset[(size_t)(r0 + tid)*NT + tn];
    __syncthreads();
    {
      int rr = tid >> 5, kp = (tid & 31)*2;
      float rv = RLC[rr], onem = 1.f - rv;
      int k1 = kp + 1;
      float v0 = (kp < 32) ? (STOL[rr*32+kp]*onem + S0L[kp]*rv)
               : (kp < 38 ? action[((size_t)(r0+rr)*NT + tn)*6 + kp-32]*onem : 0.f);
      float v1 = (k1 < 32) ? (STOL[rr*32+k1]*onem + S0L[k1]*rv)
               : (k1 < 38 ? action[((size_t)(r0+rr)*NT + tn)*6 + k1-32]*onem : 0.f);
      *(u32*)(CIN + rr*72 + kp) = pk2(v0, v1);
    }
    __syncthreads();
    f32x4 ai[4];
    for (int f = 0; f < 4; ++f) ai[f] = fz;
    for (int kk = 0; kk < 2; ++kk) {
      bf16x8 af = *(const bf16x8*)(CIN + l15*72 + kk*32 + lk*8);
      for (int f = 0; f < 4; ++f) {
        bf16x8 bf = *(const bf16x8*)(WINP + bswz(w*4 + f, 2, kk, l));
        ai[f] = mfma16(af, bf, ai[f]);
      }
    }
    for (int r = 0; r < 4; ++r) {
      float s1 = 0.f, s2 = 0.f;
      for (int f = 0; f < 4; ++f) { float v = ai[f][r]; s1 += v; s2 += v*v; }
      for (int d = 1; d < 16; d <<= 1) { s1 += __shfl_xor(s1, d); s2 += __shfl_xor(s2, d); }
      if (l15 == 0) { LNB[w][lk*4 + r][0] = s1; LNB[w][lk*4 + r][1] = s2; }
    }
    __syncthreads();
    float mr[4], ir[4];
    for (int r = 0; r < 4; ++r) {
      int row = lk*4 + r;
      float S1 = 0.f, S2 = 0.f;
      for (int wv = 0; wv < 8; ++wv) { S1 += LNB[wv][row][0]; S2 += LNB[wv][row][1]; }
      float m = S1 * (1.f/512.f);
      float var = S2 * (1.f/512.f) - m*m;
      mr[r] = m; ir[r] = rsqrtf(var + 1e-3f);
    }
    for (int f = 0; f < 4; ++f) {
      int col = w*64 + f*16 + l15;
      float gg = g_inp[col], bb = b_inp[col];
      for (int r = 0; r < 4; ++r)
        XX[(size_t)(r0 + lk*4 + r)*512 + col] = f2b(siluf((ai[f][r] - mr[r]) * ir[r] * gg + bb));
    }
  }
}

// ---------------- post: prior branch for all (b,t), double-buffered staging ----------------
__global__ __launch_bounds__(256) void k_p3(
    const float* __restrict__ g_img, const float* __restrict__ b_img,
    const float* __restrict__ b_ims, const float* __restrict__ nprior,
    float* __restrict__ out, char* __restrict__ ws) {
  const u16* wimgT = (const u16*)(ws + OFF_WIMGT);
  const u16* wimsT = (const u16*)(ws + OFF_WIMST);
  __shared__ u16 AL[2][32 * 40];
  __shared__ u16 HL[32 * 520];
  __shared__ float LNB[4][32][2];
  __shared__ float STL[32 * 64];
  const int tid = threadIdx.x;
  const int mb = blockIdx.x;   // 0..1023
  const int w = tid >> 6, l = tid & 63, l15 = l & 15, lk = l >> 4;
  const f32x4 fz = {0.f,0.f,0.f,0.f};
  f32x4 acc[2][8];
  for (int rb = 0; rb < 2; ++rb) for (int f = 0; f < 8; ++f) acc[rb][f] = fz;
  const int srow = tid >> 3, sko = (tid & 7) * 4;
  const float* sbase = out + (size_t)(mb*32 + srow)*704 + 192 + sko;  // deter_n
  const int aoff = srow*40 + sko;
  {
    float4 v = *(const float4*)(sbase);
    uint2 q; q.x = pk2(v.x, v.y); q.y = pk2(v.z, v.w);
    *(uint2*)(AL[0] + aoff) = q;
  }
  float4 vp = *(const float4*)(sbase + 32);
  __syncthreads();
  for (int kk = 0; kk < 16; ++kk) {
    if (kk < 15) {
      uint2 q; q.x = pk2(vp.x, vp.y); q.y = pk2(vp.z, vp.w);
      *(uint2*)(AL[(kk+1)&1] + aoff) = q;
    }
    if (kk < 14) vp = *(const float4*)(sbase + (kk+2)*32);
    const u16* ALc = AL[kk&1];
    bf16x8 af0 = *(const bf16x8*)(ALc + l15*40 + lk*8);
    bf16x8 af1 = *(const bf16x8*)(ALc + (16 + l15)*40 + lk*8);
    for (int f = 0; f < 8; ++f) {
      bf16x8 bf = *(const bf16x8*)(wimgT + bswz(w*8 + f, 16, kk, l));
      acc[0][f] = mfma16(af0, bf, acc[0][f]);
      acc[1][f] = mfma16(af1, bf, acc[1][f]);
    }
    __syncthreads();
  }
  for (int rb = 0; rb < 2; ++rb) {
    for (int r = 0; r < 4; ++r) {
      float s1 = 0.f, s2 = 0.f;
      for (int f = 0; f < 8; ++f) { float v = acc[rb][f][r]; s1 += v; s2 += v*v; }
      for (int d = 1; d < 16; d <<= 1) { s1 += __shfl_xor(s1, d); s2 += __shfl_xor(s2, d); }
      if (l15 == 0) { LNB[w][rb*16 + lk*4 + r][0] = s1; LNB[w][rb*16 + lk*4 + r][1] = s2; }
    }
  }
  __syncthreads();
  for (int rb = 0; rb < 2; ++rb) {
    float mr[4], ir[4];
    for (int r = 0; r < 4; ++r) {
      int row = rb*16 + lk*4 + r;
      float S1 = LNB[0][row][0] + LNB[1][row][0] + LNB[2][row][0] + LNB[3][row][0];
      float S2 = LNB[0][row][1] + LNB[1][row][1] + LNB[2][row][1] + LNB[3][row][1];
      float m = S1 * (1.f/512.f);
      float var = S2 * (1.f/512.f) - m*m;
      mr[r] = m; ir[r] = rsqrtf(var + 1e-3f);
    }
    for (int f = 0; f < 8; ++f) {
      int col = w*128 + f*16 + l15;
      float gg = g_img[col], bb = b_img[col];
      for (int r = 0; r < 4; ++r) {
        float v = siluf((acc[rb][f][r] - mr[r]) * ir[r] * gg + bb);
        HL[(rb*16 + lk*4 + r)*520 + col] = f2b(v);
      }
    }
  }
  __syncthreads();
  f32x4 q0 = fz, q1 = fz;
  for (int kk = 0; kk < 16; ++kk) {
    bf16x8 bf = *(const bf16x8*)(wimsT + bswz(w, 16, kk, l));
    bf16x8 af0 = *(const bf16x8*)(HL + l15*520 + kk*32 + lk*8);
    bf16x8 af1 = *(const bf16x8*)(HL + (16 + l15)*520 + kk*32 + lk*8);
    q0 = mfma16(af0, bf, q0);
    q1 = mfma16(af1, bf, q1);
  }
  float bia = b_ims[w*16 + l15];
  for (int r = 0; r < 4; ++r) {
    STL[(lk*4 + r)*64 + w*16 + l15] = q0[r] + bia;
    STL[(16 + lk*4 + r)*64 + w*16 + l15] = q1[r] + bia;
  }
  __syncthreads();
  for (int it = tid; it < 1024; it += 256) {
    int row = it >> 5, i = it & 31;
    int grow = mb*32 + row;
    int bb = grow >> 6, tt = grow & 63;
    float pm = STL[row*64 + i];
    float ps = softplusf(STL[row*64 + 32 + i]) + 0.1f;
    float nr = nprior[((size_t)tt*512 + bb)*32 + i];
    float pst = pm + ps*nr;
    size_t ob = (size_t)grow*704;
    out[ob + 96 + i] = pm;
    out[ob + 128 + i] = ps;
    out[ob + 160 + i] = pst;
  }
}

extern "C" void kernel_launch(void* const* d_in, const int* in_sizes, int n_in,
                              void* d_out, int out_size, void* d_ws, size_t ws_size,
                              hipStream_t stream) {
  const float* embed   = (const float*)d_in[0];
  const float* action  = (const float*)d_in[1];
  const float* reset   = (const float*)d_in[2];
  const float* npost   = (const float*)d_in[3];
  const float* nprior  = (const float*)d_in[4];
  const float* W_inp   = (const float*)d_in[5];
  const float* g_inp   = (const float*)d_in[6];
  const float* b_inp   = (const float*)d_in[7];
  const float* W_gru   = (const float*)d_in[8];
  const float* W_img   = (const float*)d_in[9];
  const float* g_img   = (const float*)d_in[10];
  const float* b_img   = (const float*)d_in[11];
  const float* W_obs   = (const float*)d_in[12];
  const float* g_obs   = (const float*)d_in[13];
  const float* b_obs   = (const float*)d_in[14];
  const float* W_ims   = (const float*)d_in[15];
  const float* b_ims   = (const float*)d_in[16];
  const float* W_ostat = (const float*)d_in[17];
  const float* b_ostat = (const float*)d_in[18];
  const float* W_init  = (const float*)d_in[19];
  float* out = (float*)d_out;
  char* ws = (char*)d_ws;
  if (ws_size < WS_NEED) return;

  k_convert<<<11648, 256, 0, stream>>>(W_inp, W_gru, W_img, W_obs, W_ims, W_ostat, ws);
  k_init_a<<<1, 256, 0, stream>>>(W_init, W_img, g_img, b_img, W_ims, b_ims, ws);
  k_phase1<<<1024, 256, 0, stream>>>(embed, ws);
  k_px0<<<32, 512, 0, stream>>>(action, reset, g_inp, b_inp, ws);
  for (int t = 0; t < NT; ++t) {
    k_gru<<<256, 256, 0, stream>>>(reset, out, ws, t);
    k_obsA<<<256, 256, 0, stream>>>(ws, t);
    k_obsB<<<32, 512, 0, stream>>>(action, reset, g_inp, b_inp, g_obs, b_obs,
                                   b_ostat, npost, out, ws, t);
  }
  k_p3<<<1024, 256, 0, stream>>>(g_img, b_img, b_ims, nprior, out, ws);
}